// Round 1
// baseline (265.170 us; speedup 1.0000x reference)
//
#include <hip/hip_runtime.h>

// Problem constants
#define BB 4
#define SS 2048
#define DIMM 512
#define HH 8
#define DD 64
#define NQKV 1536   // 3*512

typedef float  floatx4 __attribute__((ext_vector_type(4)));
typedef short  bf16x8  __attribute__((ext_vector_type(8)));   // 8 bf16 (4 VGPRs)

#define MFMA16(A, B, C) __builtin_amdgcn_mfma_f32_16x16x32_bf16(A, B, C, 0, 0, 0)

__device__ __forceinline__ unsigned short f2bf(float f) {
    unsigned int u = __float_as_uint(f);
    u += 0x7FFFu + ((u >> 16) & 1u);   // RNE
    return (unsigned short)(u >> 16);
}

// async global->LDS, 16B per lane; LDS dest = wave-uniform base + lane*16
__device__ __forceinline__ void gl_lds16(const void* g, void* l) {
    __builtin_amdgcn_global_load_lds(
        (__attribute__((address_space(1))) void*)g,
        (__attribute__((address_space(3))) void*)l,
        16, 0, 0);
}

// ---------------- convert x (fp32 -> bf16), elementwise ----------------
__global__ __launch_bounds__(256) void k_cvt_x(const float* __restrict__ x,
                                               unsigned short* __restrict__ xb) {
    int i = (blockIdx.x * 256 + threadIdx.x) * 4;
    float4 v = *(const float4*)(x + i);
    ushort4 o;
    o.x = f2bf(v.x); o.y = f2bf(v.y); o.z = f2bf(v.z); o.w = f2bf(v.w);
    *(ushort4*)(xb + i) = o;
}

// ------------- transpose+convert: in[R][C] fp32 -> out[C][R] bf16 -------------
__global__ __launch_bounds__(256) void k_tr_cvt(const float* __restrict__ in,
                                                unsigned short* __restrict__ out,
                                                int R, int C) {
    __shared__ float t[32][33];
    int c0 = blockIdx.x * 32, r0 = blockIdx.y * 32;
    int tx = threadIdx.x, ty = threadIdx.y;       // 32 x 8
    for (int i = 0; i < 4; i++) {
        int r = r0 + ty + i * 8;
        t[ty + i * 8][tx] = in[(size_t)r * C + c0 + tx];
    }
    __syncthreads();
    for (int i = 0; i < 4; i++) {
        int c = c0 + ty + i * 8;
        out[(size_t)c * R + r0 + tx] = f2bf(t[tx][ty + i * 8]);
    }
}

// ---------------- QKV GEMM: C[8192,1536] = xb[8192,512] @ Wq_t[1536,512]^T ----------------
// epilogue scatters to Q [BH][S][64], K [BH][S][64], Vt [BH][64][S] (bf16)
__global__ __launch_bounds__(256) void k_gemm_qkv(
    const unsigned short* __restrict__ A,    // [8192][512] bf16
    const unsigned short* __restrict__ Bt,   // [1536][512] bf16 (n-major)
    unsigned short* __restrict__ Qb,
    unsigned short* __restrict__ Kb,
    unsigned short* __restrict__ Vt) {
    __shared__ unsigned short As[128 * 32];
    __shared__ unsigned short Bs[128 * 32];
    const int K = 512;
    int m0 = blockIdx.x * 128, n0 = blockIdx.y * 128;
    int tid = threadIdx.x;
    int w = tid >> 6, lane = tid & 63;
    int c = lane & 15, q4 = lane >> 4;
    int wm = w >> 1, wn = w & 1;

    floatx4 acc[4][4] = {};

    for (int k0 = 0; k0 < K; k0 += 32) {
        __syncthreads();
        for (int i = 0; i < 2; i++) {
            int cidx = w * 128 + i * 64 + lane;
            int row = cidx >> 2, cc = cidx & 3;
            gl_lds16(A + (size_t)(m0 + row) * K + k0 + cc * 8,
                     As + (size_t)(w * 128 + i * 64) * 8);
            gl_lds16(Bt + (size_t)(n0 + row) * K + k0 + cc * 8,
                     Bs + (size_t)(w * 128 + i * 64) * 8);
        }
        __syncthreads();
        bf16x8 aF[4], bF[4];
        for (int mt = 0; mt < 4; mt++)
            aF[mt] = *(const bf16x8*)&As[(wm * 64 + mt * 16 + c) * 32 + q4 * 8];
        for (int nt = 0; nt < 4; nt++)
            bF[nt] = *(const bf16x8*)&Bs[(wn * 64 + nt * 16 + c) * 32 + q4 * 8];
        for (int mt = 0; mt < 4; mt++)
            for (int nt = 0; nt < 4; nt++)
                acc[mt][nt] = MFMA16(aF[mt], bF[nt], acc[mt][nt]);
    }

    // epilogue: C/D layout col=lane&15, row=(lane>>4)*4+reg
    for (int nt = 0; nt < 4; nt++) {
        int n = n0 + wn * 64 + nt * 16 + c;
        int t = n >> 9, inner = n & 511;
        int h = inner >> 6, d = inner & 63;
        for (int mt = 0; mt < 4; mt++) {
            for (int r = 0; r < 4; r++) {
                int m = m0 + wm * 64 + mt * 16 + q4 * 4 + r;
                int b = m >> 11, s = m & 2047;
                int bh = b * 8 + h;
                unsigned short val = f2bf(acc[mt][nt][r]);
                if (t == 0)       Qb[((size_t)bh * SS + s) * 64 + d] = val;
                else if (t == 1)  Kb[((size_t)bh * SS + s) * 64 + d] = val;
                else              Vt[((size_t)bh * 64 + d) * SS + s] = val;
            }
        }
    }
}

// ---------------- flash attention ----------------
// grid (S/64, H, B), 256 thr. Wave w handles Q rows q0+w*16 .. +16.
__global__ __launch_bounds__(256) void k_attn(
    const unsigned short* __restrict__ Qb,   // [BH][S][64]
    const unsigned short* __restrict__ Kb,   // [BH][S][64]
    const unsigned short* __restrict__ Vt,   // [BH][64][S]
    const float* __restrict__ log_temp,
    unsigned short* __restrict__ AO) {       // [B][S][512]
    __shared__ unsigned short Ks[64 * 64];     // [j][d]
    __shared__ unsigned short Vs[64 * 64];     // [d][j]
    __shared__ unsigned short Ps[4 * 16 * 64]; // per wave [16 m][64 j]
    int q0 = blockIdx.x * 64;
    int h = blockIdx.y, b = blockIdx.z;
    int bh = b * 8 + h;
    int tid = threadIdx.x, w = tid >> 6, lane = tid & 63;
    int c = lane & 15, q4 = lane >> 4;
    float temp = __expf(log_temp[0]);

    // Q A-frags (held in registers for whole kernel)
    bf16x8 qf[2];
    {
        const unsigned short* qp = Qb + ((size_t)bh * SS + q0 + w * 16 + c) * 64;
        qf[0] = *(const bf16x8*)(qp + q4 * 8);
        qf[1] = *(const bf16x8*)(qp + 32 + q4 * 8);
    }

    floatx4 o[4] = {};
    float mrow[4] = {-1e30f, -1e30f, -1e30f, -1e30f};
    float lrow[4] = {0.f, 0.f, 0.f, 0.f};

    for (int j0 = 0; j0 < SS; j0 += 64) {
        __syncthreads();
        for (int i = 0; i < 2; i++) {
            int cidx = w * 128 + i * 64 + lane;
            int row = cidx >> 3, cc = cidx & 7;
            gl_lds16(Kb + ((size_t)bh * SS + j0 + row) * 64 + cc * 8,
                     Ks + (size_t)(w * 128 + i * 64) * 8);
            gl_lds16(Vt + ((size_t)bh * 64 + row) * SS + j0 + cc * 8,
                     Vs + (size_t)(w * 128 + i * 64) * 8);
        }
        __syncthreads();

        // scores S[16 x 64] = Q @ K^T
        floatx4 sa[4] = {};
        for (int kh = 0; kh < 2; kh++)
            for (int nt = 0; nt < 4; nt++) {
                bf16x8 kf = *(const bf16x8*)&Ks[(nt * 16 + c) * 64 + kh * 32 + q4 * 8];
                sa[nt] = MFMA16(qf[kh], kf, sa[nt]);
            }

        // scale + diagonal mask + online softmax (rows live at (q4,reg))
        float p[4][4];     // [nt][r]
        float alpha[4];
        for (int r = 0; r < 4; r++) {
            int qrow = q0 + w * 16 + q4 * 4 + r;
            float mx = -1e30f;
            for (int nt = 0; nt < 4; nt++) {
                float s = sa[nt][r] * temp;
                if (j0 + nt * 16 + c == qrow) s = -1e30f;   // mask diagonal
                p[nt][r] = s;
                mx = fmaxf(mx, s);
            }
            mx = fmaxf(mx, __shfl_xor(mx, 1));
            mx = fmaxf(mx, __shfl_xor(mx, 2));
            mx = fmaxf(mx, __shfl_xor(mx, 4));
            mx = fmaxf(mx, __shfl_xor(mx, 8));
            float mnew = fmaxf(mrow[r], mx);
            alpha[r] = __expf(mrow[r] - mnew);
            float sum = 0.f;
            for (int nt = 0; nt < 4; nt++) {
                float e = __expf(p[nt][r] - mnew);
                p[nt][r] = e;
                sum += e;
            }
            sum += __shfl_xor(sum, 1);
            sum += __shfl_xor(sum, 2);
            sum += __shfl_xor(sum, 4);
            sum += __shfl_xor(sum, 8);
            lrow[r] = lrow[r] * alpha[r] + sum;
            mrow[r] = mnew;
        }

        // P: C-layout -> LDS -> A-layout (per-wave region, no barrier needed)
        for (int nt = 0; nt < 4; nt++)
            for (int r = 0; r < 4; r++)
                Ps[w * 1024 + (q4 * 4 + r) * 64 + nt * 16 + c] = f2bf(p[nt][r]);
        for (int dt = 0; dt < 4; dt++)
            for (int r = 0; r < 4; r++)
                o[dt][r] *= alpha[r];

        bf16x8 pa[2];
        pa[0] = *(const bf16x8*)&Ps[w * 1024 + c * 64 + q4 * 8];
        pa[1] = *(const bf16x8*)&Ps[w * 1024 + c * 64 + 32 + q4 * 8];
        for (int kh = 0; kh < 2; kh++)
            for (int dt = 0; dt < 4; dt++) {
                bf16x8 vf = *(const bf16x8*)&Vs[(dt * 16 + c) * 64 + kh * 32 + q4 * 8];
                o[dt] = MFMA16(pa[kh], vf, o[dt]);
            }
    }

    // finalize: divide by l, write [B][S][512] bf16
    for (int r = 0; r < 4; r++) {
        float inv = 1.0f / lrow[r];
        int s = q0 + w * 16 + q4 * 4 + r;
        for (int dt = 0; dt < 4; dt++)
            AO[((size_t)b * SS + s) * 512 + h * 64 + dt * 16 + c] =
                f2bf(o[dt][r] * inv);
    }
}

// ---------------- output GEMM: out[8192,512] = AO @ Wo_t^T + bias (fp32 out) ----------------
__global__ __launch_bounds__(256) void k_gemm_out(
    const unsigned short* __restrict__ A,    // [8192][512] bf16
    const unsigned short* __restrict__ Bt,   // [512][512] bf16 (n-major)
    const float* __restrict__ bias,
    float* __restrict__ out) {
    __shared__ unsigned short As[128 * 32];
    __shared__ unsigned short Bs[128 * 32];
    const int K = 512;
    int m0 = blockIdx.x * 128, n0 = blockIdx.y * 128;
    int tid = threadIdx.x;
    int w = tid >> 6, lane = tid & 63;
    int c = lane & 15, q4 = lane >> 4;
    int wm = w >> 1, wn = w & 1;

    floatx4 acc[4][4] = {};

    for (int k0 = 0; k0 < K; k0 += 32) {
        __syncthreads();
        for (int i = 0; i < 2; i++) {
            int cidx = w * 128 + i * 64 + lane;
            int row = cidx >> 2, cc = cidx & 3;
            gl_lds16(A + (size_t)(m0 + row) * K + k0 + cc * 8,
                     As + (size_t)(w * 128 + i * 64) * 8);
            gl_lds16(Bt + (size_t)(n0 + row) * K + k0 + cc * 8,
                     Bs + (size_t)(w * 128 + i * 64) * 8);
        }
        __syncthreads();
        bf16x8 aF[4], bF[4];
        for (int mt = 0; mt < 4; mt++)
            aF[mt] = *(const bf16x8*)&As[(wm * 64 + mt * 16 + c) * 32 + q4 * 8];
        for (int nt = 0; nt < 4; nt++)
            bF[nt] = *(const bf16x8*)&Bs[(wn * 64 + nt * 16 + c) * 32 + q4 * 8];
        for (int mt = 0; mt < 4; mt++)
            for (int nt = 0; nt < 4; nt++)
                acc[mt][nt] = MFMA16(aF[mt], bF[nt], acc[mt][nt]);
    }

    for (int nt = 0; nt < 4; nt++) {
        int n = n0 + wn * 64 + nt * 16 + c;
        float bv = bias[n];
        for (int mt = 0; mt < 4; mt++) {
            for (int r = 0; r < 4; r++) {
                int m = m0 + wm * 64 + mt * 16 + q4 * 4 + r;
                out[(size_t)m * 512 + n] = acc[mt][nt][r] + bv;
            }
        }
    }
}

extern "C" void kernel_launch(void* const* d_in, const int* in_sizes, int n_in,
                              void* d_out, int out_size, void* d_ws, size_t ws_size,
                              hipStream_t stream) {
    const float* x        = (const float*)d_in[0];
    const float* W_qkv    = (const float*)d_in[1];
    const float* log_temp = (const float*)d_in[2];
    const float* W_out    = (const float*)d_in[3];
    const float* b_out    = (const float*)d_in[4];
    float* out = (float*)d_out;

    char* ws = (char*)d_ws;
    // workspace layout (bytes)
    unsigned short* xb   = (unsigned short*)(ws + 0);          //  8 MB  [8192][512]
    unsigned short* Wq_t = (unsigned short*)(ws + 8388608);    //  1.5MB [1536][512]
    unsigned short* Wo_t = (unsigned short*)(ws + 9961472);    //  0.5MB [512][512]
    unsigned short* Qb   = (unsigned short*)(ws + 10485760);   //  8 MB  [32][2048][64]
    unsigned short* Kb   = (unsigned short*)(ws + 18874368);   //  8 MB  [32][2048][64]
    unsigned short* Vt   = (unsigned short*)(ws + 27262976);   //  8 MB  [32][64][2048]
    unsigned short* AO   = (unsigned short*)(ws + 35651584);   //  8 MB  [8192][512]

    k_cvt_x<<<4096, 256, 0, stream>>>(x, xb);
    k_tr_cvt<<<dim3(48, 16), dim3(32, 8), 0, stream>>>(W_qkv, Wq_t, 512, 1536);
    k_tr_cvt<<<dim3(16, 16), dim3(32, 8), 0, stream>>>(W_out, Wo_t, 512, 512);
    k_gemm_qkv<<<dim3(64, 12), 256, 0, stream>>>(xb, Wq_t, Qb, Kb, Vt);
    k_attn<<<dim3(32, 8, 4), 256, 0, stream>>>(Qb, Kb, Vt, log_temp, AO);
    k_gemm_out<<<dim3(64, 4), 256, 0, stream>>>(AO, Wo_t, b_out, out);
}

// Round 2
// 188.976 us; speedup vs baseline: 1.4032x; 1.4032x over previous
//
#include <hip/hip_runtime.h>

// Problem constants
#define BB 4
#define SS 2048
#define DIMM 512
#define HH 8
#define DD 64
#define NQKV 1536   // 3*512

typedef float  floatx4 __attribute__((ext_vector_type(4)));
typedef short  bf16x8  __attribute__((ext_vector_type(8)));   // 8 bf16 (4 VGPRs)

#define MFMA16(A, B, C) __builtin_amdgcn_mfma_f32_16x16x32_bf16(A, B, C, 0, 0, 0)

__device__ __forceinline__ unsigned short f2bf(float f) {
    unsigned int u = __float_as_uint(f);
    u += 0x7FFFu + ((u >> 16) & 1u);   // RNE
    return (unsigned short)(u >> 16);
}

// async global->LDS, 16B per lane; LDS dest = wave-uniform base + lane*16
__device__ __forceinline__ void gl_lds16(const void* g, void* l) {
    __builtin_amdgcn_global_load_lds(
        (__attribute__((address_space(1))) void*)g,
        (__attribute__((address_space(3))) void*)l,
        16, 0, 0);
}

// ---------------- convert x (fp32 -> bf16), elementwise ----------------
__global__ __launch_bounds__(256) void k_cvt_x(const float* __restrict__ x,
                                               unsigned short* __restrict__ xb) {
    int i = (blockIdx.x * 256 + threadIdx.x) * 4;
    float4 v = *(const float4*)(x + i);
    ushort4 o;
    o.x = f2bf(v.x); o.y = f2bf(v.y); o.z = f2bf(v.z); o.w = f2bf(v.w);
    *(ushort4*)(xb + i) = o;
}

// ------------- transpose+convert: in[R][C] fp32 -> out[C][R] bf16 -------------
__global__ __launch_bounds__(256) void k_tr_cvt(const float* __restrict__ in,
                                                unsigned short* __restrict__ out,
                                                int R, int C) {
    __shared__ float t[32][33];
    int c0 = blockIdx.x * 32, r0 = blockIdx.y * 32;
    int tx = threadIdx.x, ty = threadIdx.y;       // 32 x 8
    for (int i = 0; i < 4; i++) {
        int r = r0 + ty + i * 8;
        t[ty + i * 8][tx] = in[(size_t)r * C + c0 + tx];
    }
    __syncthreads();
    for (int i = 0; i < 4; i++) {
        int c = c0 + ty + i * 8;
        out[(size_t)c * R + r0 + tx] = f2bf(t[tx][ty + i * 8]);
    }
}

// ---------------- QKV GEMM: C[8192,1536] = xb[8192,512] @ Wq_t[1536,512]^T ----------------
// BK=64, XOR-swizzled LDS (chunk' = chunk ^ (row&7)) -> conflict-free ds_read_b128.
// epilogue scatters to Q [BH][S][64], K [BH][S][64], Vt [BH][64][S] (bf16)
__global__ __launch_bounds__(256) void k_gemm_qkv(
    const unsigned short* __restrict__ A,    // [8192][512] bf16
    const unsigned short* __restrict__ Bt,   // [1536][512] bf16 (n-major)
    unsigned short* __restrict__ Qb,
    unsigned short* __restrict__ Kb,
    unsigned short* __restrict__ Vt) {
    __shared__ unsigned short As[128 * 64];   // 16 KB
    __shared__ unsigned short Bs[128 * 64];   // 16 KB
    const int K = 512;
    int m0 = blockIdx.x * 128, n0 = blockIdx.y * 128;
    int tid = threadIdx.x;
    int w = tid >> 6, lane = tid & 63;
    int c = lane & 15, q4 = lane >> 4;
    int wm = w >> 1, wn = w & 1;

    floatx4 acc[4][4] = {};

    for (int k0 = 0; k0 < K; k0 += 64) {
        __syncthreads();
        for (int i = 0; i < 4; i++) {
            int cidx = w * 256 + i * 64 + lane;   // 0..1023 chunk index
            int row = cidx >> 3, cc = cidx & 7;
            int gcc = cc ^ (row & 7);             // swizzle
            gl_lds16(A + (size_t)(m0 + row) * K + k0 + gcc * 8,
                     As + (size_t)(w * 256 + i * 64) * 8);
            gl_lds16(Bt + (size_t)(n0 + row) * K + k0 + gcc * 8,
                     Bs + (size_t)(w * 256 + i * 64) * 8);
        }
        __syncthreads();
        bf16x8 aF[2][4], bF[2][4];
        for (int kh = 0; kh < 2; kh++)
            for (int mt = 0; mt < 4; mt++) {
                int row = wm * 64 + mt * 16 + c;
                aF[kh][mt] = *(const bf16x8*)&As[row * 64 + (((kh * 4 + q4) ^ (row & 7)) * 8)];
            }
        for (int kh = 0; kh < 2; kh++)
            for (int nt = 0; nt < 4; nt++) {
                int row = wn * 64 + nt * 16 + c;
                bF[kh][nt] = *(const bf16x8*)&Bs[row * 64 + (((kh * 4 + q4) ^ (row & 7)) * 8)];
            }
        for (int kh = 0; kh < 2; kh++)
            for (int mt = 0; mt < 4; mt++)
                for (int nt = 0; nt < 4; nt++)
                    acc[mt][nt] = MFMA16(aF[kh][mt], bF[kh][nt], acc[mt][nt]);
    }

    // epilogue: C/D layout col=lane&15, row=(lane>>4)*4+reg
    for (int nt = 0; nt < 4; nt++) {
        int n = n0 + wn * 64 + nt * 16 + c;
        int t = n >> 9, inner = n & 511;
        int h = inner >> 6, d = inner & 63;
        for (int mt = 0; mt < 4; mt++) {
            for (int r = 0; r < 4; r++) {
                int m = m0 + wm * 64 + mt * 16 + q4 * 4 + r;
                int b = m >> 11, s = m & 2047;
                int bh = b * 8 + h;
                unsigned short val = f2bf(acc[mt][nt][r]);
                if (t == 0)       Qb[((size_t)bh * SS + s) * 64 + d] = val;
                else if (t == 1)  Kb[((size_t)bh * SS + s) * 64 + d] = val;
                else              Vt[((size_t)bh * 64 + d) * SS + s] = val;
            }
        }
    }
}

// ---------------- flash attention (no-max softmax, MFMA row sums) ----------------
// grid (S/128, H, B), 256 thr. Wave w handles Q rows q0+w*32 .. +32 (2 m-tiles).
__global__ __launch_bounds__(256) void k_attn(
    const unsigned short* __restrict__ Qb,   // [BH][S][64]
    const unsigned short* __restrict__ Kb,   // [BH][S][64]
    const unsigned short* __restrict__ Vt,   // [BH][64][S]
    const float* __restrict__ log_temp,
    unsigned short* __restrict__ AO) {       // [B][S][512]
    __shared__ unsigned short Ks[64 * 64];       // [j][d], swizzled chunks
    __shared__ unsigned short Vs[64 * 64];       // [d][j], swizzled chunks
    __shared__ unsigned short Ps[4][16 * 64];    // per wave [16 m][64 j], swizzled
    int q0 = blockIdx.x * 128;
    int h = blockIdx.y, b = blockIdx.z;
    int bh = b * 8 + h;
    int tid = threadIdx.x, w = tid >> 6, lane = tid & 63;
    int c = lane & 15, q4 = lane >> 4;
    float temp = __expf(log_temp[0]);

    // Q A-frags for 2 m-tiles (held in registers for whole kernel)
    bf16x8 qf[2][2];
    for (int m = 0; m < 2; m++) {
        const unsigned short* qp = Qb + ((size_t)bh * SS + q0 + w * 32 + m * 16 + c) * 64;
        qf[m][0] = *(const bf16x8*)(qp + q4 * 8);
        qf[m][1] = *(const bf16x8*)(qp + 32 + q4 * 8);
    }
    // ones B-frag: column n=0 all 1.0 -> row-sum MFMA
    bf16x8 ones;
    {
        short o1 = (c == 0) ? (short)0x3F80 : (short)0;
        for (int j = 0; j < 8; j++) ones[j] = o1;
    }

    floatx4 oacc[2][4] = {};
    floatx4 lacc[2] = {};

    for (int j0 = 0; j0 < SS; j0 += 64) {
        __syncthreads();
        for (int i = 0; i < 2; i++) {
            int cidx = w * 128 + i * 64 + lane;   // 0..511 chunk index
            int row = cidx >> 3, cc = cidx & 7;
            int gcc = cc ^ (row & 7);             // swizzle
            gl_lds16(Kb + ((size_t)bh * SS + j0 + row) * 64 + gcc * 8,
                     Ks + (size_t)(w * 128 + i * 64) * 8);
            gl_lds16(Vt + ((size_t)bh * 64 + row) * SS + j0 + gcc * 8,
                     Vs + (size_t)(w * 128 + i * 64) * 8);
        }
        __syncthreads();

        // K/V B-frags (shared across both m-tiles), conflict-free reads
        bf16x8 kf[2][4], vf[2][4];
        for (int kh = 0; kh < 2; kh++)
            for (int nt = 0; nt < 4; nt++) {
                int row = nt * 16 + c;
                int sw = ((kh * 4 + q4) ^ (row & 7)) * 8;
                kf[kh][nt] = *(const bf16x8*)&Ks[row * 64 + sw];
                vf[kh][nt] = *(const bf16x8*)&Vs[row * 64 + sw];
            }

        for (int m = 0; m < 2; m++) {
            // scores S[16 x 64] = Q @ K^T
            floatx4 sa[4] = {};
            for (int kh = 0; kh < 2; kh++)
                for (int nt = 0; nt < 4; nt++)
                    sa[nt] = MFMA16(qf[m][kh], kf[kh][nt], sa[nt]);

            int rowbase = q0 + w * 32 + m * 16 + q4 * 4;
            // exp (no max subtraction -- scores ~N(0,1), safe) + diag mask -> Ps
            for (int nt = 0; nt < 4; nt++)
                for (int r = 0; r < 4; r++) {
                    float e = __expf(sa[nt][r] * temp);
                    if (j0 + nt * 16 + c == rowbase + r) e = 0.f;  // diagonal mask
                    int mm = q4 * 4 + r, jj = nt * 16 + c;
                    Ps[w][mm * 64 + (((jj >> 3) ^ (mm & 7)) * 8) + (jj & 7)] = f2bf(e);
                }

            // P: LDS -> A-layout frags (conflict-free)
            bf16x8 pa0 = *(const bf16x8*)&Ps[w][c * 64 + ((q4 ^ (c & 7)) * 8)];
            bf16x8 pa1 = *(const bf16x8*)&Ps[w][c * 64 + (((4 + q4) ^ (c & 7)) * 8)];

            // row sums via ones-MFMA (replaces shuffle reduction)
            lacc[m] = MFMA16(pa0, ones, lacc[m]);
            lacc[m] = MFMA16(pa1, ones, lacc[m]);
            // PV accumulate
            for (int dt = 0; dt < 4; dt++) {
                oacc[m][dt] = MFMA16(pa0, vf[0][dt], oacc[m][dt]);
                oacc[m][dt] = MFMA16(pa1, vf[1][dt], oacc[m][dt]);
            }
        }
    }

    // finalize: l lives in D column 0 (lanes c==0); broadcast within quarter
    for (int m = 0; m < 2; m++)
        for (int r = 0; r < 4; r++) {
            float l = __shfl(lacc[m][r], q4 << 4, 64);
            float inv = 1.0f / l;
            int s = q0 + w * 32 + m * 16 + q4 * 4 + r;
            for (int dt = 0; dt < 4; dt++)
                AO[((size_t)b * SS + s) * 512 + h * 64 + dt * 16 + c] =
                    f2bf(oacc[m][dt][r] * inv);
        }
}

// ---------------- output GEMM: out[8192,512] = AO @ Wo_t^T + bias (fp32 out) ----------------
__global__ __launch_bounds__(256) void k_gemm_out(
    const unsigned short* __restrict__ A,    // [8192][512] bf16
    const unsigned short* __restrict__ Bt,   // [512][512] bf16 (n-major)
    const float* __restrict__ bias,
    float* __restrict__ out) {
    __shared__ unsigned short As[128 * 64];
    __shared__ unsigned short Bs[128 * 64];
    const int K = 512;
    int m0 = blockIdx.x * 128, n0 = blockIdx.y * 128;
    int tid = threadIdx.x;
    int w = tid >> 6, lane = tid & 63;
    int c = lane & 15, q4 = lane >> 4;
    int wm = w >> 1, wn = w & 1;

    floatx4 acc[4][4] = {};

    for (int k0 = 0; k0 < K; k0 += 64) {
        __syncthreads();
        for (int i = 0; i < 4; i++) {
            int cidx = w * 256 + i * 64 + lane;
            int row = cidx >> 3, cc = cidx & 7;
            int gcc = cc ^ (row & 7);
            gl_lds16(A + (size_t)(m0 + row) * K + k0 + gcc * 8,
                     As + (size_t)(w * 256 + i * 64) * 8);
            gl_lds16(Bt + (size_t)(n0 + row) * K + k0 + gcc * 8,
                     Bs + (size_t)(w * 256 + i * 64) * 8);
        }
        __syncthreads();
        bf16x8 aF[2][4], bF[2][4];
        for (int kh = 0; kh < 2; kh++)
            for (int mt = 0; mt < 4; mt++) {
                int row = wm * 64 + mt * 16 + c;
                aF[kh][mt] = *(const bf16x8*)&As[row * 64 + (((kh * 4 + q4) ^ (row & 7)) * 8)];
            }
        for (int kh = 0; kh < 2; kh++)
            for (int nt = 0; nt < 4; nt++) {
                int row = wn * 64 + nt * 16 + c;
                bF[kh][nt] = *(const bf16x8*)&Bs[row * 64 + (((kh * 4 + q4) ^ (row & 7)) * 8)];
            }
        for (int kh = 0; kh < 2; kh++)
            for (int mt = 0; mt < 4; mt++)
                for (int nt = 0; nt < 4; nt++)
                    acc[mt][nt] = MFMA16(aF[kh][mt], bF[kh][nt], acc[mt][nt]);
    }

    for (int nt = 0; nt < 4; nt++) {
        int n = n0 + wn * 64 + nt * 16 + c;
        float bv = bias[n];
        for (int mt = 0; mt < 4; mt++) {
            for (int r = 0; r < 4; r++) {
                int m = m0 + wm * 64 + mt * 16 + q4 * 4 + r;
                out[(size_t)m * 512 + n] = acc[mt][nt][r] + bv;
            }
        }
    }
}

extern "C" void kernel_launch(void* const* d_in, const int* in_sizes, int n_in,
                              void* d_out, int out_size, void* d_ws, size_t ws_size,
                              hipStream_t stream) {
    const float* x        = (const float*)d_in[0];
    const float* W_qkv    = (const float*)d_in[1];
    const float* log_temp = (const float*)d_in[2];
    const float* W_out    = (const float*)d_in[3];
    const float* b_out    = (const float*)d_in[4];
    float* out = (float*)d_out;

    char* ws = (char*)d_ws;
    // workspace layout (bytes)
    unsigned short* xb   = (unsigned short*)(ws + 0);          //  8 MB  [8192][512]
    unsigned short* Wq_t = (unsigned short*)(ws + 8388608);    //  1.5MB [1536][512]
    unsigned short* Wo_t = (unsigned short*)(ws + 9961472);    //  0.5MB [512][512]
    unsigned short* Qb   = (unsigned short*)(ws + 10485760);   //  8 MB  [32][2048][64]
    unsigned short* Kb   = (unsigned short*)(ws + 18874368);   //  8 MB  [32][2048][64]
    unsigned short* Vt   = (unsigned short*)(ws + 27262976);   //  8 MB  [32][64][2048]
    unsigned short* AO   = (unsigned short*)(ws + 35651584);   //  8 MB  [8192][512]

    k_cvt_x<<<4096, 256, 0, stream>>>(x, xb);
    k_tr_cvt<<<dim3(48, 16), dim3(32, 8), 0, stream>>>(W_qkv, Wq_t, 512, 1536);
    k_tr_cvt<<<dim3(16, 16), dim3(32, 8), 0, stream>>>(W_out, Wo_t, 512, 512);
    k_gemm_qkv<<<dim3(64, 12), 256, 0, stream>>>(xb, Wq_t, Qb, Kb, Vt);
    k_attn<<<dim3(16, 8, 4), 256, 0, stream>>>(Qb, Kb, Vt, log_temp, AO);
    k_gemm_out<<<dim3(64, 4), 256, 0, stream>>>(AO, Wo_t, b_out, out);
}

// Round 3
// 171.344 us; speedup vs baseline: 1.5476x; 1.1029x over previous
//
#include <hip/hip_runtime.h>

// Problem constants
#define BB 4
#define SS 2048
#define DIMM 512
#define HH 8
#define DD 64
#define NQKV 1536   // 3*512

typedef float  floatx4 __attribute__((ext_vector_type(4)));
typedef short  bf16x8  __attribute__((ext_vector_type(8)));   // 8 bf16 (4 VGPRs)

#define MFMA16(A, B, C) __builtin_amdgcn_mfma_f32_16x16x32_bf16(A, B, C, 0, 0, 0)

__device__ __forceinline__ unsigned short f2bf(float f) {
    unsigned int u = __float_as_uint(f);
    u += 0x7FFFu + ((u >> 16) & 1u);   // RNE
    return (unsigned short)(u >> 16);
}

__device__ __forceinline__ float fast_exp2(float x) {
#if __has_builtin(__builtin_amdgcn_exp2f)
    return __builtin_amdgcn_exp2f(x);
#else
    return __exp2f(x);
#endif
}

// async global->LDS, 16B per lane; LDS dest = wave-uniform base + lane*16
__device__ __forceinline__ void gl_lds16(const void* g, void* l) {
    __builtin_amdgcn_global_load_lds(
        (__attribute__((address_space(1))) void*)g,
        (__attribute__((address_space(3))) void*)l,
        16, 0, 0);
}

// ---------------- convert x (fp32 -> bf16), elementwise ----------------
__global__ __launch_bounds__(256) void k_cvt_x(const float* __restrict__ x,
                                               unsigned short* __restrict__ xb) {
    int i = (blockIdx.x * 256 + threadIdx.x) * 4;
    float4 v = *(const float4*)(x + i);
    ushort4 o;
    o.x = f2bf(v.x); o.y = f2bf(v.y); o.z = f2bf(v.z); o.w = f2bf(v.w);
    *(ushort4*)(xb + i) = o;
}

// ------------- transpose+convert: in[R][C] fp32 -> out[C][R] bf16 -------------
__global__ __launch_bounds__(256) void k_tr_cvt(const float* __restrict__ in,
                                                unsigned short* __restrict__ out,
                                                int R, int C) {
    __shared__ float t[32][33];
    int c0 = blockIdx.x * 32, r0 = blockIdx.y * 32;
    int tx = threadIdx.x, ty = threadIdx.y;       // 32 x 8
    for (int i = 0; i < 4; i++) {
        int r = r0 + ty + i * 8;
        t[ty + i * 8][tx] = in[(size_t)r * C + c0 + tx];
    }
    __syncthreads();
    for (int i = 0; i < 4; i++) {
        int c = c0 + ty + i * 8;
        out[(size_t)c * R + r0 + tx] = f2bf(t[tx][ty + i * 8]);
    }
}

// ---------------- QKV GEMM: C[8192,1536] = xb[8192,512] @ Wq_t[1536,512]^T ----------------
// BK=64, XOR-swizzled LDS (chunk' = chunk ^ (row&7)) -> conflict-free ds_read_b128.
// epilogue scatters to Q [BH][S][64] (pre-scaled by temp*log2e), K [BH][S][64],
// Vt [BH][64][S] (bf16)
__global__ __launch_bounds__(256) void k_gemm_qkv(
    const unsigned short* __restrict__ A,    // [8192][512] bf16
    const unsigned short* __restrict__ Bt,   // [1536][512] bf16 (n-major)
    const float* __restrict__ log_temp,
    unsigned short* __restrict__ Qb,
    unsigned short* __restrict__ Kb,
    unsigned short* __restrict__ Vt) {
    __shared__ unsigned short As[128 * 64];   // 16 KB
    __shared__ unsigned short Bs[128 * 64];   // 16 KB
    const int K = 512;
    int m0 = blockIdx.x * 128, n0 = blockIdx.y * 128;
    int tid = threadIdx.x;
    int w = tid >> 6, lane = tid & 63;
    int c = lane & 15, q4 = lane >> 4;
    int wm = w >> 1, wn = w & 1;
    float qscale = __expf(log_temp[0]) * 1.44269504f;  // temp * log2(e), folded into Q

    floatx4 acc[4][4] = {};

    for (int k0 = 0; k0 < K; k0 += 64) {
        __syncthreads();
        for (int i = 0; i < 4; i++) {
            int cidx = w * 256 + i * 64 + lane;   // 0..1023 chunk index
            int row = cidx >> 3, cc = cidx & 7;
            int gcc = cc ^ (row & 7);             // swizzle
            gl_lds16(A + (size_t)(m0 + row) * K + k0 + gcc * 8,
                     As + (size_t)(w * 256 + i * 64) * 8);
            gl_lds16(Bt + (size_t)(n0 + row) * K + k0 + gcc * 8,
                     Bs + (size_t)(w * 256 + i * 64) * 8);
        }
        __syncthreads();
        bf16x8 aF[2][4], bF[2][4];
        for (int kh = 0; kh < 2; kh++)
            for (int mt = 0; mt < 4; mt++) {
                int row = wm * 64 + mt * 16 + c;
                aF[kh][mt] = *(const bf16x8*)&As[row * 64 + (((kh * 4 + q4) ^ (row & 7)) * 8)];
            }
        for (int kh = 0; kh < 2; kh++)
            for (int nt = 0; nt < 4; nt++) {
                int row = wn * 64 + nt * 16 + c;
                bF[kh][nt] = *(const bf16x8*)&Bs[row * 64 + (((kh * 4 + q4) ^ (row & 7)) * 8)];
            }
        for (int kh = 0; kh < 2; kh++)
            for (int mt = 0; mt < 4; mt++)
                for (int nt = 0; nt < 4; nt++)
                    acc[mt][nt] = MFMA16(aF[kh][mt], bF[kh][nt], acc[mt][nt]);
    }

    // epilogue: C/D layout col=lane&15, row=(lane>>4)*4+reg
    for (int nt = 0; nt < 4; nt++) {
        int n = n0 + wn * 64 + nt * 16 + c;
        int t = n >> 9, inner = n & 511;
        int h = inner >> 6, d = inner & 63;
        for (int mt = 0; mt < 4; mt++) {
            for (int r = 0; r < 4; r++) {
                int m = m0 + wm * 64 + mt * 16 + q4 * 4 + r;
                int b = m >> 11, s = m & 2047;
                int bh = b * 8 + h;
                float v = acc[mt][nt][r];
                if (t == 0)       Qb[((size_t)bh * SS + s) * 64 + d] = f2bf(v * qscale);
                else if (t == 1)  Kb[((size_t)bh * SS + s) * 64 + d] = f2bf(v);
                else              Vt[((size_t)bh * 64 + d) * SS + s] = f2bf(v);
            }
        }
    }
}

// ---------------- flash attention (no-max softmax, MFMA row sums) ----------------
// grid (S/128, H, B), 512 thr (8 waves). Wave w handles Q rows q0+w*16 .. +16.
// Q is pre-scaled by temp*log2e, so P = exp2(S) directly.
__global__ __launch_bounds__(512, 4) void k_attn(
    const unsigned short* __restrict__ Qb,   // [BH][S][64], pre-scaled
    const unsigned short* __restrict__ Kb,   // [BH][S][64]
    const unsigned short* __restrict__ Vt,   // [BH][64][S]
    unsigned short* __restrict__ AO) {       // [B][S][512]
    __shared__ unsigned short Ks[64 * 64];       // [j][d], swizzled chunks
    __shared__ unsigned short Vs[64 * 64];       // [d][j], swizzled chunks
    __shared__ unsigned short Ps[8][16 * 64];    // per wave [16 m][64 j], swizzled
    int q0 = blockIdx.x * 128;
    int h = blockIdx.y, b = blockIdx.z;
    int bh = b * 8 + h;
    int tid = threadIdx.x, w = tid >> 6, lane = tid & 63;
    int c = lane & 15, q4 = lane >> 4;

    const unsigned short* Kbase = Kb + (size_t)bh * SS * 64;
    const unsigned short* Vbase = Vt + (size_t)bh * 64 * SS;

    // Q A-frag (held in registers for whole kernel)
    bf16x8 qf[2];
    {
        const unsigned short* qp = Qb + ((size_t)bh * SS + q0 + w * 16 + c) * 64;
        qf[0] = *(const bf16x8*)(qp + q4 * 8);
        qf[1] = *(const bf16x8*)(qp + 32 + q4 * 8);
    }
    // ones B-frag: column n=0 all 1.0 -> row-sum MFMA
    bf16x8 ones;
    {
        short o1 = (c == 0) ? (short)0x3F80 : (short)0;
        for (int j = 0; j < 8; j++) ones[j] = o1;
    }

    // staging addresses: 512 lanes cover 512 K-chunks + 512 V-chunks (16B each)
    int gl = w * 64 + lane;                 // 0..511
    int grow = gl >> 3, gcc = (gl & 7) ^ (grow & 7);
    const unsigned short* ksrc = Kbase + (size_t)grow * 64 + gcc * 8;  // + j0*64/iter
    const unsigned short* vsrc = Vbase + (size_t)grow * SS + gcc * 8;  // + j0/iter
    unsigned short* kdst = Ks + w * 512;
    unsigned short* vdst = Vs + w * 512;

    int mask_j0 = (q0 + w * 16) & ~63;      // the one j-window containing the diagonal
    int rowbase = q0 + w * 16 + q4 * 4;

    floatx4 oacc[4] = {};
    floatx4 lacc = {};

    for (int j0 = 0; j0 < SS; j0 += 64) {
        __syncthreads();
        gl_lds16(ksrc + (size_t)j0 * 64, kdst);
        gl_lds16(vsrc + j0, vdst);
        __syncthreads();

        // K/V B-frags, conflict-free reads
        bf16x8 kf[2][4], vf[2][4];
        for (int kh = 0; kh < 2; kh++)
            for (int nt = 0; nt < 4; nt++) {
                int row = nt * 16 + c;
                int sw = ((kh * 4 + q4) ^ (row & 7)) * 8;
                kf[kh][nt] = *(const bf16x8*)&Ks[row * 64 + sw];
                vf[kh][nt] = *(const bf16x8*)&Vs[row * 64 + sw];
            }

        // scores S[16 x 64] = Q @ K^T (scale already folded in)
        floatx4 sa[4] = {};
        for (int kh = 0; kh < 2; kh++)
            for (int nt = 0; nt < 4; nt++)
                sa[nt] = MFMA16(qf[kh], kf[kh][nt], sa[nt]);

        // diagonal mask: wave-uniform branch, taken 1/32 iterations
        if (j0 == mask_j0) {
            for (int nt = 0; nt < 4; nt++)
                for (int r = 0; r < 4; r++)
                    if (j0 + nt * 16 + c == rowbase + r) sa[nt][r] = -1e30f;
        }

        // P = exp2(S) -> Ps (bf16, swizzled)
        for (int nt = 0; nt < 4; nt++)
            for (int r = 0; r < 4; r++) {
                float e = fast_exp2(sa[nt][r]);
                int mm = q4 * 4 + r, jj = nt * 16 + c;
                Ps[w][mm * 64 + (((jj >> 3) ^ (mm & 7)) * 8) + (jj & 7)] = f2bf(e);
            }

        // P: LDS -> A-layout frags (conflict-free)
        bf16x8 pa0 = *(const bf16x8*)&Ps[w][c * 64 + ((q4 ^ (c & 7)) * 8)];
        bf16x8 pa1 = *(const bf16x8*)&Ps[w][c * 64 + (((4 + q4) ^ (c & 7)) * 8)];

        // row sums via ones-MFMA
        lacc = MFMA16(pa0, ones, lacc);
        lacc = MFMA16(pa1, ones, lacc);
        // PV accumulate
        for (int dt = 0; dt < 4; dt++) {
            oacc[dt] = MFMA16(pa0, vf[0][dt], oacc[dt]);
            oacc[dt] = MFMA16(pa1, vf[1][dt], oacc[dt]);
        }
    }

    // finalize: l lives in D column 0 (lanes c==0); broadcast within quarter
    for (int r = 0; r < 4; r++) {
        float l = __shfl(lacc[r], q4 << 4, 64);
        float inv = 1.0f / l;
        int s = q0 + w * 16 + q4 * 4 + r;
        for (int dt = 0; dt < 4; dt++)
            AO[((size_t)b * SS + s) * 512 + h * 64 + dt * 16 + c] =
                f2bf(oacc[dt][r] * inv);
    }
}

// ---------------- output GEMM: out[8192,512] = AO @ Wo_t^T + bias (fp32 out) ----------------
__global__ __launch_bounds__(256) void k_gemm_out(
    const unsigned short* __restrict__ A,    // [8192][512] bf16
    const unsigned short* __restrict__ Bt,   // [512][512] bf16 (n-major)
    const float* __restrict__ bias,
    float* __restrict__ out) {
    __shared__ unsigned short As[128 * 64];
    __shared__ unsigned short Bs[128 * 64];
    const int K = 512;
    int m0 = blockIdx.x * 128, n0 = blockIdx.y * 128;
    int tid = threadIdx.x;
    int w = tid >> 6, lane = tid & 63;
    int c = lane & 15, q4 = lane >> 4;
    int wm = w >> 1, wn = w & 1;

    floatx4 acc[4][4] = {};

    for (int k0 = 0; k0 < K; k0 += 64) {
        __syncthreads();
        for (int i = 0; i < 4; i++) {
            int cidx = w * 256 + i * 64 + lane;
            int row = cidx >> 3, cc = cidx & 7;
            int gcc = cc ^ (row & 7);
            gl_lds16(A + (size_t)(m0 + row) * K + k0 + gcc * 8,
                     As + (size_t)(w * 256 + i * 64) * 8);
            gl_lds16(Bt + (size_t)(n0 + row) * K + k0 + gcc * 8,
                     Bs + (size_t)(w * 256 + i * 64) * 8);
        }
        __syncthreads();
        bf16x8 aF[2][4], bF[2][4];
        for (int kh = 0; kh < 2; kh++)
            for (int mt = 0; mt < 4; mt++) {
                int row = wm * 64 + mt * 16 + c;
                aF[kh][mt] = *(const bf16x8*)&As[row * 64 + (((kh * 4 + q4) ^ (row & 7)) * 8)];
            }
        for (int kh = 0; kh < 2; kh++)
            for (int nt = 0; nt < 4; nt++) {
                int row = wn * 64 + nt * 16 + c;
                bF[kh][nt] = *(const bf16x8*)&Bs[row * 64 + (((kh * 4 + q4) ^ (row & 7)) * 8)];
            }
        for (int kh = 0; kh < 2; kh++)
            for (int mt = 0; mt < 4; mt++)
                for (int nt = 0; nt < 4; nt++)
                    acc[mt][nt] = MFMA16(aF[kh][mt], bF[kh][nt], acc[mt][nt]);
    }

    for (int nt = 0; nt < 4; nt++) {
        int n = n0 + wn * 64 + nt * 16 + c;
        float bv = bias[n];
        for (int mt = 0; mt < 4; mt++) {
            for (int r = 0; r < 4; r++) {
                int m = m0 + wm * 64 + mt * 16 + q4 * 4 + r;
                out[(size_t)m * 512 + n] = acc[mt][nt][r] + bv;
            }
        }
    }
}

extern "C" void kernel_launch(void* const* d_in, const int* in_sizes, int n_in,
                              void* d_out, int out_size, void* d_ws, size_t ws_size,
                              hipStream_t stream) {
    const float* x        = (const float*)d_in[0];
    const float* W_qkv    = (const float*)d_in[1];
    const float* log_temp = (const float*)d_in[2];
    const float* W_out    = (const float*)d_in[3];
    const float* b_out    = (const float*)d_in[4];
    float* out = (float*)d_out;

    char* ws = (char*)d_ws;
    // workspace layout (bytes)
    unsigned short* xb   = (unsigned short*)(ws + 0);          //  8 MB  [8192][512]
    unsigned short* Wq_t = (unsigned short*)(ws + 8388608);    //  1.5MB [1536][512]
    unsigned short* Wo_t = (unsigned short*)(ws + 9961472);    //  0.5MB [512][512]
    unsigned short* Qb   = (unsigned short*)(ws + 10485760);   //  8 MB  [32][2048][64]
    unsigned short* Kb   = (unsigned short*)(ws + 18874368);   //  8 MB  [32][2048][64]
    unsigned short* Vt   = (unsigned short*)(ws + 27262976);   //  8 MB  [32][64][2048]
    unsigned short* AO   = (unsigned short*)(ws + 35651584);   //  8 MB  [8192][512]

    k_cvt_x<<<4096, 256, 0, stream>>>(x, xb);
    k_tr_cvt<<<dim3(48, 16), dim3(32, 8), 0, stream>>>(W_qkv, Wq_t, 512, 1536);
    k_tr_cvt<<<dim3(16, 16), dim3(32, 8), 0, stream>>>(W_out, Wo_t, 512, 512);
    k_gemm_qkv<<<dim3(64, 12), 256, 0, stream>>>(xb, Wq_t, log_temp, Qb, Kb, Vt);
    k_attn<<<dim3(16, 8, 4), 512, 0, stream>>>(Qb, Kb, Vt, AO);
    k_gemm_out<<<dim3(64, 4), 256, 0, stream>>>(AO, Wo_t, b_out, out);
}

// Round 4
// 167.995 us; speedup vs baseline: 1.5784x; 1.0199x over previous
//
#include <hip/hip_runtime.h>
#include <hip/hip_bf16.h>

// Problem constants
#define BB 4
#define SS 2048
#define DIMM 512
#define HH 8
#define DD 64
#define NQKV 1536   // 3*512

typedef float  floatx4 __attribute__((ext_vector_type(4)));
typedef short  bf16x8  __attribute__((ext_vector_type(8)));   // 8 bf16 (4 VGPRs)

#define MFMA16(A, B, C) __builtin_amdgcn_mfma_f32_16x16x32_bf16(A, B, C, 0, 0, 0)

__device__ __forceinline__ unsigned short f2bf(float f) {
    unsigned int u = __float_as_uint(f);
    u += 0x7FFFu + ((u >> 16) & 1u);   // RNE
    return (unsigned short)(u >> 16);
}

// packed f32x2 -> bf16x2 (v_cvt_pk_bf16_f32 on gfx950); lo in bits[15:0]
__device__ __forceinline__ unsigned int f2bf_pk(float lo, float hi) {
    float2 f; f.x = lo; f.y = hi;
    __hip_bfloat162 h = __float22bfloat162_rn(f);
    return *reinterpret_cast<unsigned int*>(&h);
}

__device__ __forceinline__ float fast_exp2(float x) {
#if __has_builtin(__builtin_amdgcn_exp2f)
    return __builtin_amdgcn_exp2f(x);
#else
    return __exp2f(x);
#endif
}

// async global->LDS, 16B per lane; LDS dest = wave-uniform base + lane*16
__device__ __forceinline__ void gl_lds16(const void* g, void* l) {
    __builtin_amdgcn_global_load_lds(
        (__attribute__((address_space(1))) void*)g,
        (__attribute__((address_space(3))) void*)l,
        16, 0, 0);
}

// ---------------- convert x (fp32 -> bf16), elementwise ----------------
__global__ __launch_bounds__(256) void k_cvt_x(const float* __restrict__ x,
                                               unsigned short* __restrict__ xb) {
    int i = (blockIdx.x * 256 + threadIdx.x) * 4;
    float4 v = *(const float4*)(x + i);
    ushort4 o;
    o.x = f2bf(v.x); o.y = f2bf(v.y); o.z = f2bf(v.z); o.w = f2bf(v.w);
    *(ushort4*)(xb + i) = o;
}

// ------------- transpose+convert: in[R][C] fp32 -> out[C][R] bf16 -------------
__global__ __launch_bounds__(256) void k_tr_cvt(const float* __restrict__ in,
                                                unsigned short* __restrict__ out,
                                                int R, int C) {
    __shared__ float t[32][33];
    int c0 = blockIdx.x * 32, r0 = blockIdx.y * 32;
    int tx = threadIdx.x, ty = threadIdx.y;       // 32 x 8
    for (int i = 0; i < 4; i++) {
        int r = r0 + ty + i * 8;
        t[ty + i * 8][tx] = in[(size_t)r * C + c0 + tx];
    }
    __syncthreads();
    for (int i = 0; i < 4; i++) {
        int c = c0 + ty + i * 8;
        out[(size_t)c * R + r0 + tx] = f2bf(t[tx][ty + i * 8]);
    }
}

// ---------------- QKV GEMM: C[8192,1536] = xb[8192,512] @ Wq_t[1536,512]^T ----------------
// BK=64, XOR-swizzled LDS -> conflict-free ds_read_b128.
// Q/K blocks (n0<1024): direct scatter (32B runs). V blocks (n0>=1024): C-tile is
// transposed through reused LDS, then stored to Vt [bh][64][s] with coalesced 16B/lane.
__global__ __launch_bounds__(256) void k_gemm_qkv(
    const unsigned short* __restrict__ A,    // [8192][512] bf16
    const unsigned short* __restrict__ Bt,   // [1536][512] bf16 (n-major)
    const float* __restrict__ log_temp,
    unsigned short* __restrict__ Qb,
    unsigned short* __restrict__ Kb,
    unsigned short* __restrict__ Vt) {
    __shared__ unsigned short smem[2][128 * 64];   // As | Bs, reused for V transpose
    unsigned short* As = smem[0];
    unsigned short* Bs = smem[1];
    const int K = 512;
    int m0 = blockIdx.x * 128, n0 = blockIdx.y * 128;
    int tid = threadIdx.x;
    int w = tid >> 6, lane = tid & 63;
    int c = lane & 15, q4 = lane >> 4;
    int wm = w >> 1, wn = w & 1;
    float qscale = __expf(log_temp[0]) * 1.44269504f;  // temp * log2(e), folded into Q

    floatx4 acc[4][4] = {};

    for (int k0 = 0; k0 < K; k0 += 64) {
        __syncthreads();
        for (int i = 0; i < 4; i++) {
            int cidx = w * 256 + i * 64 + lane;   // 0..1023 chunk index
            int row = cidx >> 3, cc = cidx & 7;
            int gcc = cc ^ (row & 7);             // swizzle
            gl_lds16(A + (size_t)(m0 + row) * K + k0 + gcc * 8,
                     As + (size_t)(w * 256 + i * 64) * 8);
            gl_lds16(Bt + (size_t)(n0 + row) * K + k0 + gcc * 8,
                     Bs + (size_t)(w * 256 + i * 64) * 8);
        }
        __syncthreads();
        bf16x8 aF[2][4], bF[2][4];
        for (int kh = 0; kh < 2; kh++)
            for (int mt = 0; mt < 4; mt++) {
                int row = wm * 64 + mt * 16 + c;
                aF[kh][mt] = *(const bf16x8*)&As[row * 64 + (((kh * 4 + q4) ^ (row & 7)) * 8)];
            }
        for (int kh = 0; kh < 2; kh++)
            for (int nt = 0; nt < 4; nt++) {
                int row = wn * 64 + nt * 16 + c;
                bF[kh][nt] = *(const bf16x8*)&Bs[row * 64 + (((kh * 4 + q4) ^ (row & 7)) * 8)];
            }
        for (int kh = 0; kh < 2; kh++)
            for (int mt = 0; mt < 4; mt++)
                for (int nt = 0; nt < 4; nt++)
                    acc[mt][nt] = MFMA16(aF[kh][mt], bF[kh][nt], acc[mt][nt]);
    }

    // epilogue: C/D layout col=lane&15, row=(lane>>4)*4+reg
    if (n0 < 1024) {
        // Q/K: scatter (rows of 32B across lanes)
        for (int nt = 0; nt < 4; nt++) {
            int n = n0 + wn * 64 + nt * 16 + c;
            int t = n >> 9, inner = n & 511;
            int h = inner >> 6, d = inner & 63;
            for (int mt = 0; mt < 4; mt++) {
                for (int r = 0; r < 4; r++) {
                    int m = m0 + wm * 64 + mt * 16 + q4 * 4 + r;
                    int b = m >> 11, s = m & 2047;
                    int bh = b * 8 + h;
                    float v = acc[mt][nt][r];
                    if (t == 0)  Qb[((size_t)bh * SS + s) * 64 + d] = f2bf(v * qscale);
                    else         Kb[((size_t)bh * SS + s) * 64 + d] = f2bf(v);
                }
            }
        }
    } else {
        // V: transpose C-tile through LDS, store coalesced to Vt [bh][64][s]
        // T is [64 n][128 m] with row stride 136 elems (272 B, 16B-aligned, conflict-light)
        unsigned short* T = &smem[0][0];   // needs 64*136*2 = 17408 B <= 32768 B
        int b = m0 >> 11, s_base = m0 & 2047;
        for (int half = 0; half < 2; half++) {
            __syncthreads();
            if (wn == half) {
                for (int nt = 0; nt < 4; nt++)
                    for (int mt = 0; mt < 4; mt++)
                        for (int r = 0; r < 4; r++)
                            T[(nt * 16 + c) * 136 + wm * 64 + mt * 16 + q4 * 4 + r] =
                                f2bf(acc[mt][nt][r]);
            }
            __syncthreads();
            for (int rr = 0; rr < 4; rr++) {
                int nl = w * 16 + rr * 4 + q4;        // 0..63
                int ml = c * 8;                        // 0..120
                bf16x8 v = *(const bf16x8*)&T[nl * 136 + ml];
                int n = n0 + half * 64 + nl;           // 1024..1535
                int h = (n >> 6) - 16, d = n & 63;
                int bh = b * 8 + h;
                *(bf16x8*)(Vt + ((size_t)bh * 64 + d) * SS + s_base + ml) = v;
            }
        }
    }
}

// ---------------- flash attention (no-max softmax, MFMA row sums) ----------------
// grid (S/256, H, B), 512 thr (8 waves). Wave w handles 32 Q rows (2 m-tiles),
// sharing K/V frags across both -> halves LDS-read traffic per unit work.
// K/V staging double-buffered; prefetch issued right after the barrier so the
// barrier's vmcnt(0) drain lands on the PREVIOUS iter's prefetch.
// Q is pre-scaled by temp*log2e, so P = exp2(S) directly.
__global__ __launch_bounds__(512, 2) void k_attn(
    const unsigned short* __restrict__ Qb,   // [BH][S][64], pre-scaled
    const unsigned short* __restrict__ Kb,   // [BH][S][64]
    const unsigned short* __restrict__ Vt,   // [BH][64][S]
    unsigned short* __restrict__ AO) {       // [B][S][512]
    __shared__ unsigned short Ks[2][64 * 64];    // [buf][j][d], swizzled chunks
    __shared__ unsigned short Vs[2][64 * 64];    // [buf][d][j], swizzled chunks
    __shared__ unsigned short Ps[8][16 * 64];    // per wave [16 m][64 j], swizzled
    int q0 = blockIdx.x * 256;
    int h = blockIdx.y, b = blockIdx.z;
    int bh = b * 8 + h;
    int tid = threadIdx.x, w = tid >> 6, lane = tid & 63;
    int c = lane & 15, q4 = lane >> 4;

    const unsigned short* Kbase = Kb + (size_t)bh * SS * 64;
    const unsigned short* Vbase = Vt + (size_t)bh * 64 * SS;

    // Q A-frags for 2 m-tiles (held in registers for whole kernel)
    bf16x8 qf[2][2];
    for (int m = 0; m < 2; m++) {
        const unsigned short* qp = Qb + ((size_t)bh * SS + q0 + w * 32 + m * 16 + c) * 64;
        qf[m][0] = *(const bf16x8*)(qp + q4 * 8);
        qf[m][1] = *(const bf16x8*)(qp + 32 + q4 * 8);
    }
    // ones B-frag: column n=0 all 1.0 -> row-sum MFMA
    bf16x8 ones;
    {
        short o1 = (c == 0) ? (short)0x3F80 : (short)0;
        for (int j = 0; j < 8; j++) ones[j] = o1;
    }

    // staging: 512 lanes cover 512 K-chunks + 512 V-chunks (16B each)
    int gl = tid;                           // 0..511
    int grow = gl >> 3, gcc = (gl & 7) ^ (grow & 7);
    const unsigned short* ksrc = Kbase + (size_t)grow * 64 + gcc * 8;  // + j0*64/iter
    const unsigned short* vsrc = Vbase + (size_t)grow * SS + gcc * 8;  // + j0/iter

    int mask_j0 = (q0 + w * 32) & ~63;      // both m-tiles share this diag window
    floatx4 oacc[2][4] = {};
    floatx4 lacc[2] = {};

    // prime buffer 0
    gl_lds16(ksrc, Ks[0] + w * 512);
    gl_lds16(vsrc, Vs[0] + w * 512);

    for (int j0 = 0; j0 < SS; j0 += 64) {
        int buf = (j0 >> 6) & 1;
        __syncthreads();                    // drains last iter's prefetch (vmcnt(0))
        if (j0 + 64 < SS) {                 // prefetch next tile into other buffer
            int jn = j0 + 64;
            gl_lds16(ksrc + (size_t)jn * 64, Ks[buf ^ 1] + w * 512);
            gl_lds16(vsrc + jn, Vs[buf ^ 1] + w * 512);
        }

        // K/V frags (shared across both m-tiles), conflict-free reads
        bf16x8 kf[2][4], vf[2][4];
        for (int kh = 0; kh < 2; kh++)
            for (int nt = 0; nt < 4; nt++) {
                int row = nt * 16 + c;
                int sw = ((kh * 4 + q4) ^ (row & 7)) * 8;
                kf[kh][nt] = *(const bf16x8*)&Ks[buf][row * 64 + sw];
                vf[kh][nt] = *(const bf16x8*)&Vs[buf][row * 64 + sw];
            }

        for (int m = 0; m < 2; m++) {
            // scores S[16 x 64] = Q @ K^T (scale folded into Q)
            floatx4 sa[4] = {};
            for (int kh = 0; kh < 2; kh++)
                for (int nt = 0; nt < 4; nt++)
                    sa[nt] = MFMA16(qf[m][kh], kf[kh][nt], sa[nt]);

            int rowbase = q0 + w * 32 + m * 16 + q4 * 4;
            // diagonal mask: wave-uniform branch, taken 1/32 iterations
            if (j0 == mask_j0) {
                for (int nt = 0; nt < 4; nt++)
                    for (int r = 0; r < 4; r++)
                        if (j0 + nt * 16 + c == rowbase + r) sa[nt][r] = -1e30f;
            }

            // P = exp2(S) -> Ps (bf16, swizzled); packed converts
            for (int nt = 0; nt < 4; nt++) {
                int jj = nt * 16 + c;
                int swb = ((jj >> 3) ^ 7) & 7;   // placeholder; recomputed per row below
                (void)swb;
                for (int r = 0; r < 4; r += 2) {
                    unsigned int pk = f2bf_pk(fast_exp2(sa[nt][r]),
                                              fast_exp2(sa[nt][r + 1]));
                    int mm0 = q4 * 4 + r, mm1 = mm0 + 1;
                    Ps[w][mm0 * 64 + (((jj >> 3) ^ (mm0 & 7)) * 8) + (jj & 7)] =
                        (unsigned short)pk;
                    Ps[w][mm1 * 64 + (((jj >> 3) ^ (mm1 & 7)) * 8) + (jj & 7)] =
                        (unsigned short)(pk >> 16);
                }
            }

            // P: LDS -> A-layout frags (conflict-free)
            bf16x8 pa0 = *(const bf16x8*)&Ps[w][c * 64 + ((q4 ^ (c & 7)) * 8)];
            bf16x8 pa1 = *(const bf16x8*)&Ps[w][c * 64 + (((4 + q4) ^ (c & 7)) * 8)];

            // row sums via ones-MFMA
            lacc[m] = MFMA16(pa0, ones, lacc[m]);
            lacc[m] = MFMA16(pa1, ones, lacc[m]);
            // PV accumulate
            for (int dt = 0; dt < 4; dt++) {
                oacc[m][dt] = MFMA16(pa0, vf[0][dt], oacc[m][dt]);
                oacc[m][dt] = MFMA16(pa1, vf[1][dt], oacc[m][dt]);
            }
        }
    }

    // finalize: l lives in D column 0 (lanes c==0); broadcast within quarter
    for (int m = 0; m < 2; m++)
        for (int r = 0; r < 4; r++) {
            float l = __shfl(lacc[m][r], q4 << 4, 64);
            float inv = 1.0f / l;
            int s = q0 + w * 32 + m * 16 + q4 * 4 + r;
            for (int dt = 0; dt < 4; dt++)
                AO[((size_t)b * SS + s) * 512 + h * 64 + dt * 16 + c] =
                    f2bf(oacc[m][dt][r] * inv);
        }
}

// ---------------- output GEMM: out[8192,512] = AO @ Wo_t^T + bias (fp32 out) ----------------
__global__ __launch_bounds__(256) void k_gemm_out(
    const unsigned short* __restrict__ A,    // [8192][512] bf16
    const unsigned short* __restrict__ Bt,   // [512][512] bf16 (n-major)
    const float* __restrict__ bias,
    float* __restrict__ out) {
    __shared__ unsigned short As[128 * 64];
    __shared__ unsigned short Bs[128 * 64];
    const int K = 512;
    int m0 = blockIdx.x * 128, n0 = blockIdx.y * 128;
    int tid = threadIdx.x;
    int w = tid >> 6, lane = tid & 63;
    int c = lane & 15, q4 = lane >> 4;
    int wm = w >> 1, wn = w & 1;

    floatx4 acc[4][4] = {};

    for (int k0 = 0; k0 < K; k0 += 64) {
        __syncthreads();
        for (int i = 0; i < 4; i++) {
            int cidx = w * 256 + i * 64 + lane;
            int row = cidx >> 3, cc = cidx & 7;
            int gcc = cc ^ (row & 7);
            gl_lds16(A + (size_t)(m0 + row) * K + k0 + gcc * 8,
                     As + (size_t)(w * 256 + i * 64) * 8);
            gl_lds16(Bt + (size_t)(n0 + row) * K + k0 + gcc * 8,
                     Bs + (size_t)(w * 256 + i * 64) * 8);
        }
        __syncthreads();
        bf16x8 aF[2][4], bF[2][4];
        for (int kh = 0; kh < 2; kh++)
            for (int mt = 0; mt < 4; mt++) {
                int row = wm * 64 + mt * 16 + c;
                aF[kh][mt] = *(const bf16x8*)&As[row * 64 + (((kh * 4 + q4) ^ (row & 7)) * 8)];
            }
        for (int kh = 0; kh < 2; kh++)
            for (int nt = 0; nt < 4; nt++) {
                int row = wn * 64 + nt * 16 + c;
                bF[kh][nt] = *(const bf16x8*)&Bs[row * 64 + (((kh * 4 + q4) ^ (row & 7)) * 8)];
            }
        for (int kh = 0; kh < 2; kh++)
            for (int mt = 0; mt < 4; mt++)
                for (int nt = 0; nt < 4; nt++)
                    acc[mt][nt] = MFMA16(aF[kh][mt], bF[kh][nt], acc[mt][nt]);
    }

    for (int nt = 0; nt < 4; nt++) {
        int n = n0 + wn * 64 + nt * 16 + c;
        float bv = bias[n];
        for (int mt = 0; mt < 4; mt++) {
            for (int r = 0; r < 4; r++) {
                int m = m0 + wm * 64 + mt * 16 + q4 * 4 + r;
                out[(size_t)m * 512 + n] = acc[mt][nt][r] + bv;
            }
        }
    }
}

extern "C" void kernel_launch(void* const* d_in, const int* in_sizes, int n_in,
                              void* d_out, int out_size, void* d_ws, size_t ws_size,
                              hipStream_t stream) {
    const float* x        = (const float*)d_in[0];
    const float* W_qkv    = (const float*)d_in[1];
    const float* log_temp = (const float*)d_in[2];
    const float* W_out    = (const float*)d_in[3];
    const float* b_out    = (const float*)d_in[4];
    float* out = (float*)d_out;

    char* ws = (char*)d_ws;
    // workspace layout (bytes)
    unsigned short* xb   = (unsigned short*)(ws + 0);          //  8 MB  [8192][512]
    unsigned short* Wq_t = (unsigned short*)(ws + 8388608);    //  1.5MB [1536][512]
    unsigned short* Wo_t = (unsigned short*)(ws + 9961472);    //  0.5MB [512][512]
    unsigned short* Qb   = (unsigned short*)(ws + 10485760);   //  8 MB  [32][2048][64]
    unsigned short* Kb   = (unsigned short*)(ws + 18874368);   //  8 MB  [32][2048][64]
    unsigned short* Vt   = (unsigned short*)(ws + 27262976);   //  8 MB  [32][64][2048]
    unsigned short* AO   = (unsigned short*)(ws + 35651584);   //  8 MB  [8192][512]

    k_cvt_x<<<4096, 256, 0, stream>>>(x, xb);
    k_tr_cvt<<<dim3(48, 16), dim3(32, 8), 0, stream>>>(W_qkv, Wq_t, 512, 1536);
    k_tr_cvt<<<dim3(16, 16), dim3(32, 8), 0, stream>>>(W_out, Wo_t, 512, 512);
    k_gemm_qkv<<<dim3(64, 12), 256, 0, stream>>>(xb, Wq_t, log_temp, Qb, Kb, Vt);
    k_attn<<<dim3(8, 8, 4), 512, 0, stream>>>(Qb, Kb, Vt, AO);
    k_gemm_out<<<dim3(64, 4), 256, 0, stream>>>(AO, Wo_t, b_out, out);
}

// Round 5
// 167.931 us; speedup vs baseline: 1.5790x; 1.0004x over previous
//
#include <hip/hip_runtime.h>
#include <hip/hip_bf16.h>

// Problem constants
#define BB 4
#define SS 2048
#define DIMM 512
#define HH 8
#define DD 64
#define NQKV 1536   // 3*512

typedef float  floatx4 __attribute__((ext_vector_type(4)));
typedef short  bf16x8  __attribute__((ext_vector_type(8)));   // 8 bf16 (4 VGPRs)
typedef short  bf16x4  __attribute__((ext_vector_type(4)));   // 4 bf16 (2 VGPRs)

#define MFMA16(A, B, C) __builtin_amdgcn_mfma_f32_16x16x32_bf16(A, B, C, 0, 0, 0)

// K=16 MFMA: D = A(16x16 bf16) * B(16x16 bf16) + C. A row=lane&15,k=q4*4+i;
// B col=lane&15,k=q4*4+i; C/D col=lane&15,row=q4*4+reg.
__device__ __forceinline__ floatx4 MFMA16K16(bf16x4 a, bf16x4 b, floatx4 c) {
#if __has_builtin(__builtin_amdgcn_mfma_f32_16x16x16bf16_1k)
    return __builtin_amdgcn_mfma_f32_16x16x16bf16_1k(a, b, c, 0, 0, 0);
#else
    floatx4 d;
    asm volatile("v_mfma_f32_16x16x16_bf16 %0, %1, %2, %3"
                 : "=v"(d) : "v"(a), "v"(b), "v"(c));
    return d;
#endif
}

__device__ __forceinline__ unsigned short f2bf(float f) {
    unsigned int u = __float_as_uint(f);
    u += 0x7FFFu + ((u >> 16) & 1u);   // RNE
    return (unsigned short)(u >> 16);
}

// packed f32x2 -> bf16x2 (v_cvt_pk_bf16_f32 on gfx950); lo in bits[15:0]
__device__ __forceinline__ unsigned int f2bf_pk(float lo, float hi) {
    float2 f; f.x = lo; f.y = hi;
    __hip_bfloat162 h = __float22bfloat162_rn(f);
    return *reinterpret_cast<unsigned int*>(&h);
}

__device__ __forceinline__ float fast_exp2(float x) {
#if __has_builtin(__builtin_amdgcn_exp2f)
    return __builtin_amdgcn_exp2f(x);
#else
    return __exp2f(x);
#endif
}

// async global->LDS, 16B per lane; LDS dest = wave-uniform base + lane*16
__device__ __forceinline__ void gl_lds16(const void* g, void* l) {
    __builtin_amdgcn_global_load_lds(
        (__attribute__((address_space(1))) void*)g,
        (__attribute__((address_space(3))) void*)l,
        16, 0, 0);
}

// ---------------- fused prep: cvt x + transpose W_qkv + transpose W_out ----------------
// blocks 0..4095: x fp32->bf16. 4096..4863: W_qkv 512x1536 -> [1536][512].
// 4864..5119: W_out 512x512 -> [512][512].
__global__ __launch_bounds__(256) void k_prep(
    const float* __restrict__ x, const float* __restrict__ W_qkv,
    const float* __restrict__ W_out,
    unsigned short* __restrict__ xb, unsigned short* __restrict__ Wq_t,
    unsigned short* __restrict__ Wo_t) {
    __shared__ float t[32][33];
    int bid = blockIdx.x, tid = threadIdx.x;
    if (bid < 4096) {
        int i = (bid * 256 + tid) * 4;
        float4 v = *(const float4*)(x + i);
        ushort4 o;
        o.x = f2bf(v.x); o.y = f2bf(v.y); o.z = f2bf(v.z); o.w = f2bf(v.w);
        *(ushort4*)(xb + i) = o;
        return;
    }
    const float* in; unsigned short* out; int R = 512, C, bx, by;
    if (bid < 4864) { in = W_qkv; out = Wq_t; C = 1536; int blk = bid - 4096; bx = blk % 48; by = blk / 48; }
    else            { in = W_out; out = Wo_t; C = 512;  int blk = bid - 4864; bx = blk % 16; by = blk / 16; }
    int tx = tid & 31, ty = tid >> 5;       // 32 x 8
    int c0 = bx * 32, r0 = by * 32;
    for (int i = 0; i < 4; i++) {
        int r = r0 + ty + i * 8;
        t[ty + i * 8][tx] = in[(size_t)r * C + c0 + tx];
    }
    __syncthreads();
    for (int i = 0; i < 4; i++) {
        int cc = c0 + ty + i * 8;
        out[(size_t)cc * R + r0 + tx] = f2bf(t[tx][ty + i * 8]);
    }
}

// ---------------- QKV GEMM: C[8192,1536] = xb[8192,512] @ Wq_t[1536,512]^T ----------------
// BK=64, XOR-swizzled LDS -> conflict-free ds_read_b128.
// Q/K blocks (n0<1024): direct scatter. V blocks: transpose through LDS, coalesced store.
__global__ __launch_bounds__(256) void k_gemm_qkv(
    const unsigned short* __restrict__ A,    // [8192][512] bf16
    const unsigned short* __restrict__ Bt,   // [1536][512] bf16 (n-major)
    const float* __restrict__ log_temp,
    unsigned short* __restrict__ Qb,
    unsigned short* __restrict__ Kb,
    unsigned short* __restrict__ Vt) {
    __shared__ unsigned short smem[2][128 * 64];   // As | Bs, reused for V transpose
    unsigned short* As = smem[0];
    unsigned short* Bs = smem[1];
    const int K = 512;
    int m0 = blockIdx.x * 128, n0 = blockIdx.y * 128;
    int tid = threadIdx.x;
    int w = tid >> 6, lane = tid & 63;
    int c = lane & 15, q4 = lane >> 4;
    int wm = w >> 1, wn = w & 1;
    float qscale = __expf(log_temp[0]) * 1.44269504f;  // temp * log2(e), folded into Q

    floatx4 acc[4][4] = {};

    for (int k0 = 0; k0 < K; k0 += 64) {
        __syncthreads();
        for (int i = 0; i < 4; i++) {
            int cidx = w * 256 + i * 64 + lane;   // 0..1023 chunk index
            int row = cidx >> 3, cc = cidx & 7;
            int gcc = cc ^ (row & 7);             // swizzle
            gl_lds16(A + (size_t)(m0 + row) * K + k0 + gcc * 8,
                     As + (size_t)(w * 256 + i * 64) * 8);
            gl_lds16(Bt + (size_t)(n0 + row) * K + k0 + gcc * 8,
                     Bs + (size_t)(w * 256 + i * 64) * 8);
        }
        __syncthreads();
        bf16x8 aF[2][4], bF[2][4];
        for (int kh = 0; kh < 2; kh++)
            for (int mt = 0; mt < 4; mt++) {
                int row = wm * 64 + mt * 16 + c;
                aF[kh][mt] = *(const bf16x8*)&As[row * 64 + (((kh * 4 + q4) ^ (row & 7)) * 8)];
            }
        for (int kh = 0; kh < 2; kh++)
            for (int nt = 0; nt < 4; nt++) {
                int row = wn * 64 + nt * 16 + c;
                bF[kh][nt] = *(const bf16x8*)&Bs[row * 64 + (((kh * 4 + q4) ^ (row & 7)) * 8)];
            }
        for (int kh = 0; kh < 2; kh++)
            for (int mt = 0; mt < 4; mt++)
                for (int nt = 0; nt < 4; nt++)
                    acc[mt][nt] = MFMA16(aF[kh][mt], bF[kh][nt], acc[mt][nt]);
    }

    // epilogue: C/D layout col=lane&15, row=(lane>>4)*4+reg
    if (n0 < 1024) {
        for (int nt = 0; nt < 4; nt++) {
            int n = n0 + wn * 64 + nt * 16 + c;
            int t = n >> 9, inner = n & 511;
            int h = inner >> 6, d = inner & 63;
            for (int mt = 0; mt < 4; mt++) {
                for (int r = 0; r < 4; r++) {
                    int m = m0 + wm * 64 + mt * 16 + q4 * 4 + r;
                    int b = m >> 11, s = m & 2047;
                    int bh = b * 8 + h;
                    float v = acc[mt][nt][r];
                    if (t == 0)  Qb[((size_t)bh * SS + s) * 64 + d] = f2bf(v * qscale);
                    else         Kb[((size_t)bh * SS + s) * 64 + d] = f2bf(v);
                }
            }
        }
    } else {
        // V: transpose C-tile through LDS, store coalesced to Vt [bh][64][s]
        unsigned short* T = &smem[0][0];   // [64 n][128 m], stride 136 (17408 B)
        int b = m0 >> 11, s_base = m0 & 2047;
        for (int half = 0; half < 2; half++) {
            __syncthreads();
            if (wn == half) {
                for (int nt = 0; nt < 4; nt++)
                    for (int mt = 0; mt < 4; mt++)
                        for (int r = 0; r < 4; r++)
                            T[(nt * 16 + c) * 136 + wm * 64 + mt * 16 + q4 * 4 + r] =
                                f2bf(acc[mt][nt][r]);
            }
            __syncthreads();
            for (int rr = 0; rr < 4; rr++) {
                int nl = w * 16 + rr * 4 + q4;        // 0..63
                int ml = c * 8;                        // 0..120
                bf16x8 v = *(const bf16x8*)&T[nl * 136 + ml];
                int n = n0 + half * 64 + nl;           // 1024..1535
                int h = (n >> 6) - 16, d = n & 63;
                int bh = b * 8 + h;
                *(bf16x8*)(Vt + ((size_t)bh * 64 + d) * SS + s_base + ml) = v;
            }
        }
    }
}

// ---------------- flash attention, S^T formulation ----------------
// grid (S/128, H, B), 256 thr (4 waves). Wave w: 32 Q-rows (2 m-tiles).
// S^T = K @ Q^T via MFMA(A=K,B=Q): C-frag (col=m, row=j) == A-frag of the K=16
// MFMA -> exp2 in-register feeds PV directly, NO P LDS round-trip.
// Row sums in VALU (linear -> reduce across q4 once at end).
// Q pre-scaled by temp*log2e, so P = exp2(S).
__global__ __launch_bounds__(256, 4) void k_attn(
    const unsigned short* __restrict__ Qb,   // [BH][S][64], pre-scaled
    const unsigned short* __restrict__ Kb,   // [BH][S][64]
    const unsigned short* __restrict__ Vt,   // [BH][64][S]
    unsigned short* __restrict__ AO) {       // [B][S][512]
    __shared__ unsigned short Ks[2][64 * 64];    // [buf][j][d], swizzled chunks
    __shared__ unsigned short Vs[2][64 * 64];    // [buf][d][j], swizzled chunks
    int q0 = blockIdx.x * 128;
    int h = blockIdx.y, b = blockIdx.z;
    int bh = b * 8 + h;
    int tid = threadIdx.x, w = tid >> 6, lane = tid & 63;
    int c = lane & 15, q4 = lane >> 4;

    const unsigned short* Kbase = Kb + (size_t)bh * SS * 64;
    const unsigned short* Vbase = Vt + (size_t)bh * 64 * SS;

    // Q B-frags (K=32 layout: col m = lane&15, k = q4*8+i), 2 m-tiles
    bf16x8 qf[2][2];
    for (int mi = 0; mi < 2; mi++) {
        const unsigned short* qp = Qb + ((size_t)bh * SS + q0 + w * 32 + mi * 16 + c) * 64;
        qf[mi][0] = *(const bf16x8*)(qp + q4 * 8);
        qf[mi][1] = *(const bf16x8*)(qp + 32 + q4 * 8);
    }

    // staging: 256 lanes x 2 chunks each for K and V (512 16B-chunks per tile)
    const unsigned short* ksrc[2];
    const unsigned short* vsrc[2];
    for (int i = 0; i < 2; i++) {
        int cidx = i * 256 + tid;
        int grow = cidx >> 3, gcc = (cidx & 7) ^ (grow & 7);
        ksrc[i] = Kbase + (size_t)grow * 64 + gcc * 8;
        vsrc[i] = Vbase + (size_t)grow * SS + gcc * 8;
    }

    // prime buffer 0
    for (int i = 0; i < 2; i++) {
        gl_lds16(ksrc[i], Ks[0] + (i * 256 + w * 64) * 8);
        gl_lds16(vsrc[i], Vs[0] + (i * 256 + w * 64) * 8);
    }

    int mask_j0 = (q0 + w * 32) & ~63;       // both m-tiles share this diag window
    int mglob0 = q0 + w * 32 + c;
    int mglob1 = mglob0 + 16;
    floatx4 oacc[2][4] = {};
    float psum0 = 0.f, psum1 = 0.f;

    for (int j0 = 0; j0 < SS; j0 += 64) {
        int buf = (j0 >> 6) & 1;
        __syncthreads();                     // drains last iter's prefetch
        if (j0 + 64 < SS) {
            for (int i = 0; i < 2; i++) {
                gl_lds16(ksrc[i] + (size_t)(j0 + 64) * 64, Ks[buf ^ 1] + (i * 256 + w * 64) * 8);
                gl_lds16(vsrc[i] + (j0 + 64), Vs[buf ^ 1] + (i * 256 + w * 64) * 8);
            }
        }
        bool diag = (j0 == mask_j0);

        for (int jt = 0; jt < 4; jt++) {
            int row = jt * 16 + c;           // j within tile (A-frag row)
            bf16x8 kf0 = *(const bf16x8*)&Ks[buf][row * 64 + ((q4 ^ (row & 7)) * 8)];
            bf16x8 kf1 = *(const bf16x8*)&Ks[buf][row * 64 + (((4 + q4) ^ (row & 7)) * 8)];
            // S^T tiles: rows j, cols m
            floatx4 sa0 = {}, sa1 = {};
            sa0 = MFMA16(kf0, qf[0][0], sa0);
            sa0 = MFMA16(kf1, qf[0][1], sa0);
            sa1 = MFMA16(kf0, qf[1][0], sa1);
            sa1 = MFMA16(kf1, qf[1][1], sa1);

            if (diag) {                       // wave-uniform, 1/32 iterations
                for (int r = 0; r < 4; r++) {
                    int jg = j0 + jt * 16 + q4 * 4 + r;
                    if (jg == mglob0) sa0[r] = -1e30f;
                    if (jg == mglob1) sa1[r] = -1e30f;
                }
            }

            // exp2 in-register -> bf16x4 A-frags; accumulate row sums (over j)
            float e0 = fast_exp2(sa0[0]), e1 = fast_exp2(sa0[1]);
            float e2 = fast_exp2(sa0[2]), e3 = fast_exp2(sa0[3]);
            psum0 += (e0 + e1) + (e2 + e3);
            union { bf16x4 v; unsigned int u[2]; } P0;
            P0.u[0] = f2bf_pk(e0, e1); P0.u[1] = f2bf_pk(e2, e3);
            float f0 = fast_exp2(sa1[0]), f1 = fast_exp2(sa1[1]);
            float f2 = fast_exp2(sa1[2]), f3 = fast_exp2(sa1[3]);
            psum1 += (f0 + f1) + (f2 + f3);
            union { bf16x4 v; unsigned int u[2]; } P1;
            P1.u[0] = f2bf_pk(f0, f1); P1.u[1] = f2bf_pk(f2, f3);

            // PV: V B-frags (k=j contiguous in Vs[d][j]) via ds_read_b64
            int chunk = jt * 2 + (q4 >> 1);
            int sub = (q4 & 1) * 4;
            for (int dt = 0; dt < 4; dt++) {
                int vrow = dt * 16 + c;
                bf16x4 vf = *(const bf16x4*)&Vs[buf][vrow * 64 + ((chunk ^ (vrow & 7)) * 8) + sub];
                oacc[0][dt] = MFMA16K16(P0.v, vf, oacc[0][dt]);
                oacc[1][dt] = MFMA16K16(P1.v, vf, oacc[1][dt]);
            }
        }
    }

    // l: reduce psum across q4 groups -> lane holds l[m=c]; fetch l[row] via shuffle
    for (int mi = 0; mi < 2; mi++) {
        float l = (mi == 0) ? psum0 : psum1;
        l += __shfl_xor(l, 16);
        l += __shfl_xor(l, 32);
        for (int r = 0; r < 4; r++) {
            float lr = __shfl(l, q4 * 4 + r, 64);  // lane with c == q4*4+r
            float inv = 1.0f / lr;
            int s = q0 + w * 32 + mi * 16 + q4 * 4 + r;
            for (int dt = 0; dt < 4; dt++)
                AO[((size_t)b * SS + s) * 512 + h * 64 + dt * 16 + c] =
                    f2bf(oacc[mi][dt][r] * inv);
        }
    }
}

// ---------------- output GEMM: out[8192,512] = AO @ Wo_t^T + bias (fp32 out) ----------------
__global__ __launch_bounds__(256) void k_gemm_out(
    const unsigned short* __restrict__ A,    // [8192][512] bf16
    const unsigned short* __restrict__ Bt,   // [512][512] bf16 (n-major)
    const float* __restrict__ bias,
    float* __restrict__ out) {
    __shared__ unsigned short As[128 * 64];
    __shared__ unsigned short Bs[128 * 64];
    const int K = 512;
    int m0 = blockIdx.x * 128, n0 = blockIdx.y * 128;
    int tid = threadIdx.x;
    int w = tid >> 6, lane = tid & 63;
    int c = lane & 15, q4 = lane >> 4;
    int wm = w >> 1, wn = w & 1;

    floatx4 acc[4][4] = {};

    for (int k0 = 0; k0 < K; k0 += 64) {
        __syncthreads();
        for (int i = 0; i < 4; i++) {
            int cidx = w * 256 + i * 64 + lane;
            int row = cidx >> 3, cc = cidx & 7;
            int gcc = cc ^ (row & 7);
            gl_lds16(A + (size_t)(m0 + row) * K + k0 + gcc * 8,
                     As + (size_t)(w * 256 + i * 64) * 8);
            gl_lds16(Bt + (size_t)(n0 + row) * K + k0 + gcc * 8,
                     Bs + (size_t)(w * 256 + i * 64) * 8);
        }
        __syncthreads();
        bf16x8 aF[2][4], bF[2][4];
        for (int kh = 0; kh < 2; kh++)
            for (int mt = 0; mt < 4; mt++) {
                int row = wm * 64 + mt * 16 + c;
                aF[kh][mt] = *(const bf16x8*)&As[row * 64 + (((kh * 4 + q4) ^ (row & 7)) * 8)];
            }
        for (int kh = 0; kh < 2; kh++)
            for (int nt = 0; nt < 4; nt++) {
                int row = wn * 64 + nt * 16 + c;
                bF[kh][nt] = *(const bf16x8*)&Bs[row * 64 + (((kh * 4 + q4) ^ (row & 7)) * 8)];
            }
        for (int kh = 0; kh < 2; kh++)
            for (int mt = 0; mt < 4; mt++)
                for (int nt = 0; nt < 4; nt++)
                    acc[mt][nt] = MFMA16(aF[kh][mt], bF[kh][nt], acc[mt][nt]);
    }

    for (int nt = 0; nt < 4; nt++) {
        int n = n0 + wn * 64 + nt * 16 + c;
        float bv = bias[n];
        for (int mt = 0; mt < 4; mt++) {
            for (int r = 0; r < 4; r++) {
                int m = m0 + wm * 64 + mt * 16 + q4 * 4 + r;
                out[(size_t)m * 512 + n] = acc[mt][nt][r] + bv;
            }
        }
    }
}

extern "C" void kernel_launch(void* const* d_in, const int* in_sizes, int n_in,
                              void* d_out, int out_size, void* d_ws, size_t ws_size,
                              hipStream_t stream) {
    const float* x        = (const float*)d_in[0];
    const float* W_qkv    = (const float*)d_in[1];
    const float* log_temp = (const float*)d_in[2];
    const float* W_out    = (const float*)d_in[3];
    const float* b_out    = (const float*)d_in[4];
    float* out = (float*)d_out;

    char* ws = (char*)d_ws;
    unsigned short* xb   = (unsigned short*)(ws + 0);          //  8 MB  [8192][512]
    unsigned short* Wq_t = (unsigned short*)(ws + 8388608);    //  1.5MB [1536][512]
    unsigned short* Wo_t = (unsigned short*)(ws + 9961472);    //  0.5MB [512][512]
    unsigned short* Qb   = (unsigned short*)(ws + 10485760);   //  8 MB  [32][2048][64]
    unsigned short* Kb   = (unsigned short*)(ws + 18874368);   //  8 MB  [32][2048][64]
    unsigned short* Vt   = (unsigned short*)(ws + 27262976);   //  8 MB  [32][64][2048]
    unsigned short* AO   = (unsigned short*)(ws + 35651584);   //  8 MB  [8192][512]

    k_prep<<<5120, 256, 0, stream>>>(x, W_qkv, W_out, xb, Wq_t, Wo_t);
    k_gemm_qkv<<<dim3(64, 12), 256, 0, stream>>>(xb, Wq_t, log_temp, Qb, Kb, Vt);
    k_attn<<<dim3(16, 8, 4), 256, 0, stream>>>(Qb, Kb, Vt, AO);
    k_gemm_out<<<dim3(64, 4), 256, 0, stream>>>(AO, Wo_t, b_out, out);
}

// Round 6
// 164.636 us; speedup vs baseline: 1.6106x; 1.0200x over previous
//
#include <hip/hip_runtime.h>
#include <hip/hip_bf16.h>

// Problem constants
#define BB 4
#define SS 2048
#define DIMM 512
#define HH 8
#define DD 64
#define NQKV 1536   // 3*512

typedef float  floatx4 __attribute__((ext_vector_type(4)));
typedef short  bf16x8  __attribute__((ext_vector_type(8)));   // 8 bf16 (4 VGPRs)
typedef short  bf16x4  __attribute__((ext_vector_type(4)));   // 4 bf16 (2 VGPRs)

#define MFMA16(A, B, C) __builtin_amdgcn_mfma_f32_16x16x32_bf16(A, B, C, 0, 0, 0)

// K=16 MFMA: D = A(16x16 bf16) * B(16x16 bf16) + C. A row=lane&15,k=q4*4+i;
// B col=lane&15,k=q4*4+i; C/D col=lane&15,row=q4*4+reg.
__device__ __forceinline__ floatx4 MFMA16K16(bf16x4 a, bf16x4 b, floatx4 c) {
#if __has_builtin(__builtin_amdgcn_mfma_f32_16x16x16bf16_1k)
    return __builtin_amdgcn_mfma_f32_16x16x16bf16_1k(a, b, c, 0, 0, 0);
#else
    floatx4 d;
    asm volatile("v_mfma_f32_16x16x16_bf16 %0, %1, %2, %3"
                 : "=v"(d) : "v"(a), "v"(b), "v"(c));
    return d;
#endif
}

__device__ __forceinline__ unsigned short f2bf(float f) {
    unsigned int u = __float_as_uint(f);
    u += 0x7FFFu + ((u >> 16) & 1u);   // RNE
    return (unsigned short)(u >> 16);
}

// packed f32x2 -> bf16x2 (v_cvt_pk_bf16_f32 on gfx950); lo in bits[15:0]
__device__ __forceinline__ unsigned int f2bf_pk(float lo, float hi) {
    float2 f; f.x = lo; f.y = hi;
    __hip_bfloat162 h = __float22bfloat162_rn(f);
    return *reinterpret_cast<unsigned int*>(&h);
}

__device__ __forceinline__ float fast_exp2(float x) {
#if __has_builtin(__builtin_amdgcn_exp2f)
    return __builtin_amdgcn_exp2f(x);
#else
    return __exp2f(x);
#endif
}

// async global->LDS, 16B per lane; LDS dest = wave-uniform base + lane*16
__device__ __forceinline__ void gl_lds16(const void* g, void* l) {
    __builtin_amdgcn_global_load_lds(
        (__attribute__((address_space(1))) void*)g,
        (__attribute__((address_space(3))) void*)l,
        16, 0, 0);
}

// ---------------- fused prep: cvt x + transpose W_qkv + transpose W_out ----------------
__global__ __launch_bounds__(256) void k_prep(
    const float* __restrict__ x, const float* __restrict__ W_qkv,
    const float* __restrict__ W_out,
    unsigned short* __restrict__ xb, unsigned short* __restrict__ Wq_t,
    unsigned short* __restrict__ Wo_t) {
    __shared__ float t[32][33];
    int bid = blockIdx.x, tid = threadIdx.x;
    if (bid < 4096) {
        int i = (bid * 256 + tid) * 4;
        float4 v = *(const float4*)(x + i);
        ushort4 o;
        o.x = f2bf(v.x); o.y = f2bf(v.y); o.z = f2bf(v.z); o.w = f2bf(v.w);
        *(ushort4*)(xb + i) = o;
        return;
    }
    const float* in; unsigned short* out; int R = 512, C, bx, by;
    if (bid < 4864) { in = W_qkv; out = Wq_t; C = 1536; int blk = bid - 4096; bx = blk % 48; by = blk / 48; }
    else            { in = W_out; out = Wo_t; C = 512;  int blk = bid - 4864; bx = blk % 16; by = blk / 16; }
    int tx = tid & 31, ty = tid >> 5;       // 32 x 8
    int c0 = bx * 32, r0 = by * 32;
    for (int i = 0; i < 4; i++) {
        int r = r0 + ty + i * 8;
        t[ty + i * 8][tx] = in[(size_t)r * C + c0 + tx];
    }
    __syncthreads();
    for (int i = 0; i < 4; i++) {
        int cc = c0 + ty + i * 8;
        out[(size_t)cc * R + r0 + tx] = f2bf(t[tx][ty + i * 8]);
    }
}

// ---------------- QKV GEMM: C[8192,1536] = xb[8192,512] @ Wq_t[1536,512]^T ----------------
__global__ __launch_bounds__(256) void k_gemm_qkv(
    const unsigned short* __restrict__ A,    // [8192][512] bf16
    const unsigned short* __restrict__ Bt,   // [1536][512] bf16 (n-major)
    const float* __restrict__ log_temp,
    unsigned short* __restrict__ Qb,
    unsigned short* __restrict__ Kb,
    unsigned short* __restrict__ Vt) {
    __shared__ unsigned short smem[2][128 * 64];   // As | Bs, reused for V transpose
    unsigned short* As = smem[0];
    unsigned short* Bs = smem[1];
    const int K = 512;
    int m0 = blockIdx.x * 128, n0 = blockIdx.y * 128;
    int tid = threadIdx.x;
    int w = tid >> 6, lane = tid & 63;
    int c = lane & 15, q4 = lane >> 4;
    int wm = w >> 1, wn = w & 1;
    float qscale = __expf(log_temp[0]) * 1.44269504f;  // temp * log2(e), folded into Q

    floatx4 acc[4][4] = {};

    for (int k0 = 0; k0 < K; k0 += 64) {
        __syncthreads();
        for (int i = 0; i < 4; i++) {
            int cidx = w * 256 + i * 64 + lane;   // 0..1023 chunk index
            int row = cidx >> 3, cc = cidx & 7;
            int gcc = cc ^ (row & 7);             // swizzle
            gl_lds16(A + (size_t)(m0 + row) * K + k0 + gcc * 8,
                     As + (size_t)(w * 256 + i * 64) * 8);
            gl_lds16(Bt + (size_t)(n0 + row) * K + k0 + gcc * 8,
                     Bs + (size_t)(w * 256 + i * 64) * 8);
        }
        __syncthreads();
        bf16x8 aF[2][4], bF[2][4];
        for (int kh = 0; kh < 2; kh++)
            for (int mt = 0; mt < 4; mt++) {
                int row = wm * 64 + mt * 16 + c;
                aF[kh][mt] = *(const bf16x8*)&As[row * 64 + (((kh * 4 + q4) ^ (row & 7)) * 8)];
            }
        for (int kh = 0; kh < 2; kh++)
            for (int nt = 0; nt < 4; nt++) {
                int row = wn * 64 + nt * 16 + c;
                bF[kh][nt] = *(const bf16x8*)&Bs[row * 64 + (((kh * 4 + q4) ^ (row & 7)) * 8)];
            }
        for (int kh = 0; kh < 2; kh++)
            for (int mt = 0; mt < 4; mt++)
                for (int nt = 0; nt < 4; nt++)
                    acc[mt][nt] = MFMA16(aF[kh][mt], bF[kh][nt], acc[mt][nt]);
    }

    // epilogue: C/D layout col=lane&15, row=(lane>>4)*4+reg
    if (n0 < 1024) {
        for (int nt = 0; nt < 4; nt++) {
            int n = n0 + wn * 64 + nt * 16 + c;
            int t = n >> 9, inner = n & 511;
            int h = inner >> 6, d = inner & 63;
            for (int mt = 0; mt < 4; mt++) {
                for (int r = 0; r < 4; r++) {
                    int m = m0 + wm * 64 + mt * 16 + q4 * 4 + r;
                    int b = m >> 11, s = m & 2047;
                    int bh = b * 8 + h;
                    float v = acc[mt][nt][r];
                    if (t == 0)  Qb[((size_t)bh * SS + s) * 64 + d] = f2bf(v * qscale);
                    else         Kb[((size_t)bh * SS + s) * 64 + d] = f2bf(v);
                }
            }
        }
    } else {
        // V: transpose C-tile through LDS, store coalesced to Vt [bh][64][s]
        unsigned short* T = &smem[0][0];   // [64 n][128 m], stride 136 (17408 B)
        int b = m0 >> 11, s_base = m0 & 2047;
        for (int half = 0; half < 2; half++) {
            __syncthreads();
            if (wn == half) {
                for (int nt = 0; nt < 4; nt++)
                    for (int mt = 0; mt < 4; mt++)
                        for (int r = 0; r < 4; r++)
                            T[(nt * 16 + c) * 136 + wm * 64 + mt * 16 + q4 * 4 + r] =
                                f2bf(acc[mt][nt][r]);
            }
            __syncthreads();
            for (int rr = 0; rr < 4; rr++) {
                int nl = w * 16 + rr * 4 + q4;        // 0..63
                int ml = c * 8;                        // 0..120
                bf16x8 v = *(const bf16x8*)&T[nl * 136 + ml];
                int n = n0 + half * 64 + nl;           // 1024..1535
                int h = (n >> 6) - 16, d = n & 63;
                int bh = b * 8 + h;
                *(bf16x8*)(Vt + ((size_t)bh * 64 + d) * SS + s_base + ml) = v;
            }
        }
    }
}

// ---------------- flash attention, S^T formulation, 8 waves/block ----------------
// grid (S/128, H, B) = 512 blocks, 512 thr (8 waves) -> 2 blocks/CU = 16 waves/CU.
// Wave w: 16 Q-rows. S^T = K @ Q^T: C-frag == A-frag of K=16 MFMA -> exp2 feeds
// PV in-register, no P LDS round-trip. Row sums in VALU. Q pre-scaled by temp*log2e.
__global__ __launch_bounds__(512, 4) void k_attn(
    const unsigned short* __restrict__ Qb,   // [BH][S][64], pre-scaled
    const unsigned short* __restrict__ Kb,   // [BH][S][64]
    const unsigned short* __restrict__ Vt,   // [BH][64][S]
    unsigned short* __restrict__ AO) {       // [B][S][512]
    __shared__ unsigned short Ks[2][64 * 64];    // [buf][j][d], swizzled chunks
    __shared__ unsigned short Vs[2][64 * 64];    // [buf][d][j], swizzled chunks
    int q0 = blockIdx.x * 128;
    int h = blockIdx.y, b = blockIdx.z;
    int bh = b * 8 + h;
    int tid = threadIdx.x, w = tid >> 6, lane = tid & 63;
    int c = lane & 15, q4 = lane >> 4;

    const unsigned short* Kbase = Kb + (size_t)bh * SS * 64;
    const unsigned short* Vbase = Vt + (size_t)bh * 64 * SS;

    // Q B-frags (K=32 layout: col m = lane&15, k = q4*8+i)
    bf16x8 qf[2];
    {
        const unsigned short* qp = Qb + ((size_t)bh * SS + q0 + w * 16 + c) * 64;
        qf[0] = *(const bf16x8*)(qp + q4 * 8);
        qf[1] = *(const bf16x8*)(qp + 32 + q4 * 8);
    }

    // staging: 512 lanes cover 512 K-chunks + 512 V-chunks (16B each)
    int grow = tid >> 3, gcc = (tid & 7) ^ (grow & 7);
    const unsigned short* ksrc = Kbase + (size_t)grow * 64 + gcc * 8;  // + j0*64/iter
    const unsigned short* vsrc = Vbase + (size_t)grow * SS + gcc * 8;  // + j0/iter
    unsigned short* kdst = (unsigned short*)Ks[0] + w * 512;  // +buf*4096
    unsigned short* vdst = (unsigned short*)Vs[0] + w * 512;

    // prime buffer 0
    gl_lds16(ksrc, kdst);
    gl_lds16(vsrc, vdst);

    int mask_j0 = (q0 + w * 16) & ~63;       // the diag window for this wave
    int mglob = q0 + w * 16 + c;
    floatx4 oacc[4] = {};
    float psum = 0.f;

    for (int j0 = 0; j0 < SS; j0 += 64) {
        int buf = (j0 >> 6) & 1;
        __syncthreads();                     // drains last iter's prefetch
        if (j0 + 64 < SS) {
            gl_lds16(ksrc + (size_t)(j0 + 64) * 64, kdst + (buf ^ 1) * 4096);
            gl_lds16(vsrc + (j0 + 64), vdst + (buf ^ 1) * 4096);
        }
        bool diag = (j0 == mask_j0);

        for (int jt = 0; jt < 4; jt++) {
            int row = jt * 16 + c;           // j within tile (A-frag row)
            bf16x8 kf0 = *(const bf16x8*)&Ks[buf][row * 64 + ((q4 ^ (row & 7)) * 8)];
            bf16x8 kf1 = *(const bf16x8*)&Ks[buf][row * 64 + (((4 + q4) ^ (row & 7)) * 8)];
            // S^T tile: rows j, cols m
            floatx4 sa = {};
            sa = MFMA16(kf0, qf[0], sa);
            sa = MFMA16(kf1, qf[1], sa);

            if (diag) {                       // wave-uniform, 1/32 iterations
                for (int r = 0; r < 4; r++) {
                    int jg = j0 + jt * 16 + q4 * 4 + r;
                    if (jg == mglob) sa[r] = -1e30f;
                }
            }

            // exp2 in-register -> bf16x4 A-frag; accumulate row sums (over j)
            float e0 = fast_exp2(sa[0]), e1 = fast_exp2(sa[1]);
            float e2 = fast_exp2(sa[2]), e3 = fast_exp2(sa[3]);
            psum += (e0 + e1) + (e2 + e3);
            union { bf16x4 v; unsigned int u[2]; } P;
            P.u[0] = f2bf_pk(e0, e1); P.u[1] = f2bf_pk(e2, e3);

            // PV: V B-frags (k=j contiguous in Vs[d][j]) via ds_read_b64
            int chunk = jt * 2 + (q4 >> 1);
            int sub = (q4 & 1) * 4;
            for (int dt = 0; dt < 4; dt++) {
                int vrow = dt * 16 + c;
                bf16x4 vf = *(const bf16x4*)&Vs[buf][vrow * 64 + ((chunk ^ (vrow & 7)) * 8) + sub];
                oacc[dt] = MFMA16K16(P.v, vf, oacc[dt]);
            }
        }
    }

    // l: reduce psum across q4 groups -> lane q4*4+r holds l[m=q4*4+r] at c==q4*4+r
    float l = psum;
    l += __shfl_xor(l, 16);
    l += __shfl_xor(l, 32);
    for (int r = 0; r < 4; r++) {
        float lr = __shfl(l, q4 * 4 + r, 64);
        float inv = 1.0f / lr;
        int s = q0 + w * 16 + q4 * 4 + r;
        for (int dt = 0; dt < 4; dt++)
            AO[((size_t)b * SS + s) * 512 + h * 64 + dt * 16 + c] =
                f2bf(oacc[dt][r] * inv);
    }
}

// ---------------- output GEMM: out[8192,512] = AO @ Wo_t^T + bias (fp32 out) ----------------
// 64x128 tiles, grid (128,4)=512 blocks -> 2 blocks/CU (was 1).
__global__ __launch_bounds__(256) void k_gemm_out(
    const unsigned short* __restrict__ A,    // [8192][512] bf16
    const unsigned short* __restrict__ Bt,   // [512][512] bf16 (n-major)
    const float* __restrict__ bias,
    float* __restrict__ out) {
    __shared__ unsigned short As[64 * 64];    //  8 KB
    __shared__ unsigned short Bs[128 * 64];   // 16 KB
    const int K = 512;
    int m0 = blockIdx.x * 64, n0 = blockIdx.y * 128;
    int tid = threadIdx.x;
    int w = tid >> 6, lane = tid & 63;
    int c = lane & 15, q4 = lane >> 4;

    floatx4 acc[8] = {};

    for (int k0 = 0; k0 < K; k0 += 64) {
        __syncthreads();
        for (int i = 0; i < 2; i++) {
            int cidx = i * 256 + tid;             // 0..511 (As chunks)
            int row = cidx >> 3, cc = cidx & 7;
            int gcc = cc ^ (row & 7);
            gl_lds16(A + (size_t)(m0 + row) * K + k0 + gcc * 8,
                     As + (size_t)(i * 256 + w * 64) * 8);
        }
        for (int i = 0; i < 4; i++) {
            int cidx = i * 256 + tid;             // 0..1023 (Bs chunks)
            int row = cidx >> 3, cc = cidx & 7;
            int gcc = cc ^ (row & 7);
            gl_lds16(Bt + (size_t)(n0 + row) * K + k0 + gcc * 8,
                     Bs + (size_t)(i * 256 + w * 64) * 8);
        }
        __syncthreads();
        bf16x8 aF[2], bF[2][8];
        for (int kh = 0; kh < 2; kh++) {
            int row = w * 16 + c;
            aF[kh] = *(const bf16x8*)&As[row * 64 + (((kh * 4 + q4) ^ (row & 7)) * 8)];
        }
        for (int kh = 0; kh < 2; kh++)
            for (int nt = 0; nt < 8; nt++) {
                int row = nt * 16 + c;
                bF[kh][nt] = *(const bf16x8*)&Bs[row * 64 + (((kh * 4 + q4) ^ (row & 7)) * 8)];
            }
        for (int kh = 0; kh < 2; kh++)
            for (int nt = 0; nt < 8; nt++)
                acc[nt] = MFMA16(aF[kh], bF[kh][nt], acc[nt]);
    }

    for (int nt = 0; nt < 8; nt++) {
        int n = n0 + nt * 16 + c;
        float bv = bias[n];
        for (int r = 0; r < 4; r++) {
            int m = m0 + w * 16 + q4 * 4 + r;
            out[(size_t)m * 512 + n] = acc[nt][r] + bv;
        }
    }
}

extern "C" void kernel_launch(void* const* d_in, const int* in_sizes, int n_in,
                              void* d_out, int out_size, void* d_ws, size_t ws_size,
                              hipStream_t stream) {
    const float* x        = (const float*)d_in[0];
    const float* W_qkv    = (const float*)d_in[1];
    const float* log_temp = (const float*)d_in[2];
    const float* W_out    = (const float*)d_in[3];
    const float* b_out    = (const float*)d_in[4];
    float* out = (float*)d_out;

    char* ws = (char*)d_ws;
    unsigned short* xb   = (unsigned short*)(ws + 0);          //  8 MB  [8192][512]
    unsigned short* Wq_t = (unsigned short*)(ws + 8388608);    //  1.5MB [1536][512]
    unsigned short* Wo_t = (unsigned short*)(ws + 9961472);    //  0.5MB [512][512]
    unsigned short* Qb   = (unsigned short*)(ws + 10485760);   //  8 MB  [32][2048][64]
    unsigned short* Kb   = (unsigned short*)(ws + 18874368);   //  8 MB  [32][2048][64]
    unsigned short* Vt   = (unsigned short*)(ws + 27262976);   //  8 MB  [32][64][2048]
    unsigned short* AO   = (unsigned short*)(ws + 35651584);   //  8 MB  [8192][512]

    k_prep<<<5120, 256, 0, stream>>>(x, W_qkv, W_out, xb, Wq_t, Wo_t);
    k_gemm_qkv<<<dim3(64, 12), 256, 0, stream>>>(xb, Wq_t, log_temp, Qb, Kb, Vt);
    k_attn<<<dim3(16, 8, 4), 512, 0, stream>>>(Qb, Kb, Vt, AO);
    k_gemm_out<<<dim3(128, 4), 256, 0, stream>>>(AO, Wo_t, b_out, out);
}